// Round 2
// baseline (3996.257 us; speedup 1.0000x reference)
//
#include <hip/hip_runtime.h>

#define N_NODES 131072
#define N_EDGES 4194304
#define FDIM 64
#define HID 128

// ---------------------------------------------------------------------------
// Detect whether edge_index arrived as int64 (odd int32 words all zero) or
// int32. JAX without x64 silently downgrades jnp.int64 -> int32, but be robust.
__global__ void detect_i64(const int* __restrict__ ei, int* __restrict__ flag) {
    __shared__ int s_nz;
    int t = threadIdx.x;  // 0..255
    if (t == 0) s_nz = 0;
    __syncthreads();
    if (ei[2 * t + 1] != 0) atomicAdd(&s_nz, 1);
    __syncthreads();
    if (t == 0) *flag = (s_nz == 0) ? 1 : 0;  // 1 => int64 layout
}

__device__ __forceinline__ int load_idx(const void* ei, long long pos, int is64) {
    if (is64) return (int)((const long long*)ei)[pos];
    return ((const int*)ei)[pos];
}

// ---------------------------------------------------------------------------
// deg[src] += w   (segment_sum by src)
__global__ void deg_kernel(const void* __restrict__ ei, const float* __restrict__ w,
                           float* __restrict__ deg, const int* __restrict__ flag) {
    int is64 = *flag;
    long long i = (long long)blockIdx.x * blockDim.x + threadIdx.x;
    long long stride = (long long)gridDim.x * blockDim.x;
    for (long long e = i; e < N_EDGES; e += stride) {
        int s = load_idx(ei, e, is64);
        atomicAdd(&deg[s], w[e]);
    }
}

__global__ void dinv_kernel(const float* __restrict__ deg, float* __restrict__ dinv) {
    int i = blockIdx.x * blockDim.x + threadIdx.x;
    if (i < N_NODES) {
        float d = deg[i];
        dinv[i] = d > 0.f ? rsqrtf(d) : 0.f;
    }
}

// src32/dst32/norm_w materialization: norm_w = -dinv[src]*w*dinv[dst]
__global__ void prep_kernel(const void* __restrict__ ei, const float* __restrict__ w,
                            const float* __restrict__ dinv, int* __restrict__ src32,
                            int* __restrict__ dst32, float* __restrict__ nw,
                            const int* __restrict__ flag) {
    int is64 = *flag;
    long long i = (long long)blockIdx.x * blockDim.x + threadIdx.x;
    long long stride = (long long)gridDim.x * blockDim.x;
    for (long long e = i; e < N_EDGES; e += stride) {
        int s = load_idx(ei, e, is64);
        int d = load_idx(ei, N_EDGES + e, is64);
        src32[e] = s;
        dst32[e] = d;
        nw[e] = -dinv[s] * w[e] * dinv[d];
    }
}

// ---------------------------------------------------------------------------
// y[dst] += scale * nw * v[src]  — one 64-lane group per edge, lane = feature.
__global__ __launch_bounds__(256) void spmm_atomic(
    const int* __restrict__ src, const int* __restrict__ dst,
    const float* __restrict__ nw, const float* __restrict__ v,
    float* __restrict__ y, float scale) {
    int lane = threadIdx.x & 63;
    long long slot = (long long)blockIdx.x * (blockDim.x >> 6) + (threadIdx.x >> 6);
    long long nslots = (long long)gridDim.x * (blockDim.x >> 6);
    for (long long e = slot; e < N_EDGES; e += nslots) {
        int s = src[e];
        int d = dst[e];
        float w = nw[e] * scale;
        float val = w * v[(long long)s * FDIM + lane];
        atomicAdd(&y[(long long)d * FDIM + lane], val);
    }
}

// y = -a  (pre-init for Tx2 = 2*spmm(Tx1) - Tx0 etc.)
__global__ void neg_copy(const float4* __restrict__ a, float4* __restrict__ y, int n4) {
    int i = blockIdx.x * blockDim.x + threadIdx.x;
    int stride = gridDim.x * blockDim.x;
    for (int j = i; j < n4; j += stride) {
        float4 v = a[j];
        y[j] = make_float4(-v.x, -v.y, -v.z, -v.w);
    }
}

// ---------------------------------------------------------------------------
// Fused: gate preacts (z & h_tilde only; R is dead, W_h GEMMs are zero since
// H=0), activations, h=relu((1-Z)*tanh), logits=sqrt(sum h), out=h@W_lin+b.
// Block = 256 threads handles 16 nodes. Thread (nl=tid/16, m=tid%16) computes
// 8 output cols: c = p*64 + m*4 + q, p in {0,1}, q in {0..3}.
__device__ __forceinline__ void fma4(float4& acc, float t, float4 wv) {
    acc.x = fmaf(t, wv.x, acc.x);
    acc.y = fmaf(t, wv.y, acc.y);
    acc.z = fmaf(t, wv.z, acc.z);
    acc.w = fmaf(t, wv.w, acc.w);
}

__global__ __launch_bounds__(256) void gate_gemm(
    const float* __restrict__ x, const float* __restrict__ tx1,
    const float* __restrict__ tx2, const float* __restrict__ tx3,
    const float* __restrict__ Wx,   // [3][4][64][128]
    const float* __restrict__ bx,   // [3][128]
    const float* __restrict__ bh,   // [3][128]
    const float* __restrict__ Wlin, // [128]
    const float* __restrict__ blin, // [1]
    float* __restrict__ outv, float* __restrict__ logits) {
    __shared__ float txs[16][260];  // pad: node-stride 260 ≡ 4 mod 32 banks
    int tid = threadIdx.x;
    long long nodeBase = (long long)blockIdx.x * 16;

    const float* Ts[4] = {x, tx1, tx2, tx3};
#pragma unroll
    for (int k = 0; k < 4; ++k) {
        const float4* tp = (const float4*)(Ts[k] + nodeBase * FDIM);
        float4 v = tp[tid];  // 256 threads * 4 floats = 16 nodes * 64 feats
        int n = tid >> 4;
        int i0 = (tid & 15) * 4;
        txs[n][k * 64 + i0 + 0] = v.x;
        txs[n][k * 64 + i0 + 1] = v.y;
        txs[n][k * 64 + i0 + 2] = v.z;
        txs[n][k * 64 + i0 + 3] = v.w;
    }
    __syncthreads();

    int nl = tid >> 4;  // node within tile
    int m = tid & 15;   // col group
    float4 az0 = {0.f, 0.f, 0.f, 0.f}, az1 = {0.f, 0.f, 0.f, 0.f};
    float4 at0 = {0.f, 0.f, 0.f, 0.f}, at1 = {0.f, 0.f, 0.f, 0.f};

    // Combined input dim 256 (k*64+r == i). Gate0 row i at Wx + i*128,
    // gate2 row i at Wx + (512+i)*128.
    for (int i = 0; i < 256; ++i) {
        float tv = txs[nl][i];
        const float4* w0 = (const float4*)(Wx + i * HID);
        const float4* w2 = (const float4*)(Wx + (512 + i) * HID);
        float4 wa = w0[m];
        float4 wb = w0[m + 16];
        float4 wc = w2[m];
        float4 wd = w2[m + 16];
        fma4(az0, tv, wa);
        fma4(az1, tv, wb);
        fma4(at0, tv, wc);
        fma4(at1, tv, wd);
    }

    float sumh = 0.f, sumhw = 0.f;
#pragma unroll
    for (int p = 0; p < 2; ++p) {
        float azv[4] = {p ? az1.x : az0.x, p ? az1.y : az0.y, p ? az1.z : az0.z,
                        p ? az1.w : az0.w};
        float atv[4] = {p ? at1.x : at0.x, p ? at1.y : at0.y, p ? at1.z : at0.z,
                        p ? at1.w : at0.w};
        int cbase = p * 64 + m * 4;
#pragma unroll
        for (int q = 0; q < 4; ++q) {
            int c = cbase + q;
            float vz = azv[q] + bx[c] + bh[c];              // gate 0 (z)
            float vt = atv[q] + bx[256 + c] + bh[256 + c];  // gate 2 (h~)
            float zg = 1.f / (1.f + __expf(-vz));
            float ht = tanhf(vt);
            float h = (1.f - zg) * ht;
            h = h > 0.f ? h : 0.f;
            sumh += h;
            sumhw += h * Wlin[c];
        }
    }
    // reduce across the 16 lanes (m) of this node
#pragma unroll
    for (int off = 8; off >= 1; off >>= 1) {
        sumh += __shfl_xor(sumh, off, 64);
        sumhw += __shfl_xor(sumhw, off, 64);
    }
    if (m == 0) {
        long long node = nodeBase + nl;
        logits[node] = sqrtf(sumh);
        outv[node] = sumhw + blin[0];
    }
}

// ---------------------------------------------------------------------------
extern "C" void kernel_launch(void* const* d_in, const int* in_sizes, int n_in,
                              void* d_out, int out_size, void* d_ws, size_t ws_size,
                              hipStream_t stream) {
    const float* x = (const float*)d_in[0];
    const void* ei = d_in[1];  // edge_index [2,E], int32 or int64 (auto-detect)
    const float* ew = (const float*)d_in[2];
    const float* Wx = (const float*)d_in[3];
    // d_in[4] = W_h: unused (H=0 => cheb(H,...) = bias only)
    const float* bx = (const float*)d_in[5];
    const float* bh = (const float*)d_in[6];
    const float* Wlin = (const float*)d_in[7];
    const float* blin = (const float*)d_in[8];
    float* outv = (float*)d_out;             // [N] = h@W_lin + b_lin
    float* logits = (float*)d_out + N_NODES; // [N] = sqrt(sum h)

    // workspace layout (all 4-byte elems)
    float* deg = (float*)d_ws;                       // N
    float* dinv = deg + N_NODES;                     // N
    int* flag = (int*)(dinv + N_NODES);              // 64 (align pad)
    int* src32 = flag + 64;                          // E
    int* dst32 = src32 + N_EDGES;                    // E
    float* nw = (float*)(dst32 + N_EDGES);           // E
    float* tx1 = nw + N_EDGES;                       // N*64
    float* tx2 = tx1 + (size_t)N_NODES * FDIM;       // N*64
    float* tx3 = tx2 + (size_t)N_NODES * FDIM;       // N*64

    (void)hipMemsetAsync(deg, 0, N_NODES * sizeof(float), stream);
    detect_i64<<<1, 256, 0, stream>>>((const int*)ei, flag);
    deg_kernel<<<1024, 256, 0, stream>>>(ei, ew, deg, flag);
    dinv_kernel<<<N_NODES / 256, 256, 0, stream>>>(deg, dinv);
    prep_kernel<<<2048, 256, 0, stream>>>(ei, ew, dinv, src32, dst32, nw, flag);

    // Tx1 = spmm(x)
    (void)hipMemsetAsync(tx1, 0, (size_t)N_NODES * FDIM * sizeof(float), stream);
    spmm_atomic<<<8192, 256, 0, stream>>>(src32, dst32, nw, x, tx1, 1.0f);
    // Tx2 = 2*spmm(Tx1) - Tx0
    neg_copy<<<2048, 256, 0, stream>>>((const float4*)x, (float4*)tx2,
                                       N_NODES * FDIM / 4);
    spmm_atomic<<<8192, 256, 0, stream>>>(src32, dst32, nw, tx1, tx2, 2.0f);
    // Tx3 = 2*spmm(Tx2) - Tx1
    neg_copy<<<2048, 256, 0, stream>>>((const float4*)tx1, (float4*)tx3,
                                       N_NODES * FDIM / 4);
    spmm_atomic<<<8192, 256, 0, stream>>>(src32, dst32, nw, tx2, tx3, 2.0f);

    gate_gemm<<<N_NODES / 16, 256, 0, stream>>>(x, tx1, tx2, tx3, Wx, bx, bh,
                                                Wlin, blin, outv, logits);
}

// Round 3
// 1633.371 us; speedup vs baseline: 2.4466x; 2.4466x over previous
//
#include <hip/hip_runtime.h>

#define N_NODES 131072
#define N_EDGES 4194304
#define FDIM 64
#define HID 128

// ---------------------------------------------------------------------------
// Detect int64 vs int32 edge_index layout (JAX may deliver either).
__global__ void detect_i64(const int* __restrict__ ei, int* __restrict__ flag) {
    __shared__ int s_nz;
    int t = threadIdx.x;
    if (t == 0) s_nz = 0;
    __syncthreads();
    if (ei[2 * t + 1] != 0) atomicAdd(&s_nz, 1);
    __syncthreads();
    if (t == 0) *flag = (s_nz == 0) ? 1 : 0;
}

__device__ __forceinline__ int load_idx(const void* ei, long long pos, int is64) {
    if (is64) return (int)((const long long*)ei)[pos];
    return ((const int*)ei)[pos];
}

// ---------------------------------------------------------------------------
__global__ void deg_kernel(const void* __restrict__ ei, const float* __restrict__ w,
                           float* __restrict__ deg, const int* __restrict__ flag) {
    int is64 = *flag;
    long long i = (long long)blockIdx.x * blockDim.x + threadIdx.x;
    long long stride = (long long)gridDim.x * blockDim.x;
    for (long long e = i; e < N_EDGES; e += stride) {
        int s = load_idx(ei, e, is64);
        atomicAdd(&deg[s], w[e]);
    }
}

__global__ void dinv_kernel(const float* __restrict__ deg, float* __restrict__ dinv) {
    int i = blockIdx.x * blockDim.x + threadIdx.x;
    if (i < N_NODES) {
        float d = deg[i];
        dinv[i] = d > 0.f ? rsqrtf(d) : 0.f;
    }
}

// nw = -dinv[src]*w*dinv[dst], plus histogram of dst (for CSC build)
__global__ void prep_hist(const void* __restrict__ ei, const float* __restrict__ w,
                          const float* __restrict__ dinv, float* __restrict__ nw,
                          int* __restrict__ cnt, const int* __restrict__ flag) {
    int is64 = *flag;
    long long i = (long long)blockIdx.x * blockDim.x + threadIdx.x;
    long long stride = (long long)gridDim.x * blockDim.x;
    for (long long e = i; e < N_EDGES; e += stride) {
        int s = load_idx(ei, e, is64);
        int d = load_idx(ei, N_EDGES + e, is64);
        nw[e] = -dinv[s] * w[e] * dinv[d];
        atomicAdd(&cnt[d], 1);
    }
}

// ---------------------------------------------------------------------------
// 3-kernel exclusive scan over cnt[N_NODES] -> row_ptr (+cursor copy)
__global__ void scan_block_sums(const int* __restrict__ cnt, int* __restrict__ bsum) {
    __shared__ int red[256];
    int i = blockIdx.x * 256 + threadIdx.x;
    red[threadIdx.x] = cnt[i];
    __syncthreads();
    for (int off = 128; off > 0; off >>= 1) {
        if (threadIdx.x < off) red[threadIdx.x] += red[threadIdx.x + off];
        __syncthreads();
    }
    if (threadIdx.x == 0) bsum[blockIdx.x] = red[0];
}

__global__ void scan_bsums(const int* __restrict__ bsum, int* __restrict__ boff,
                           int* __restrict__ row_ptr) {
    __shared__ int tmp[512];
    int t = threadIdx.x;
    tmp[t] = bsum[t];
    __syncthreads();
    for (int off = 1; off < 512; off <<= 1) {
        int v = (t >= off) ? tmp[t - off] : 0;
        __syncthreads();
        tmp[t] += v;
        __syncthreads();
    }
    boff[t] = tmp[t] - bsum[t];  // exclusive
    if (t == 0) row_ptr[N_NODES] = N_EDGES;
}

__global__ void scan_final(const int* __restrict__ cnt, const int* __restrict__ boff,
                           int* __restrict__ row_ptr, int* __restrict__ cursor) {
    __shared__ int tmp[256];
    int t = threadIdx.x;
    int i = blockIdx.x * 256 + t;
    int c = cnt[i];
    tmp[t] = c;
    __syncthreads();
    for (int off = 1; off < 256; off <<= 1) {
        int v = (t >= off) ? tmp[t - off] : 0;
        __syncthreads();
        tmp[t] += v;
        __syncthreads();
    }
    int excl = tmp[t] - c + boff[blockIdx.x];
    row_ptr[i] = excl;
    cursor[i] = excl;
}

// Counting-sort scatter: edges grouped by dst
__global__ void scatter_edges(const void* __restrict__ ei, const float* __restrict__ nw,
                              int* __restrict__ cursor, int* __restrict__ cs_src,
                              float* __restrict__ cs_w, const int* __restrict__ flag) {
    int is64 = *flag;
    long long i = (long long)blockIdx.x * blockDim.x + threadIdx.x;
    long long stride = (long long)gridDim.x * blockDim.x;
    for (long long e = i; e < N_EDGES; e += stride) {
        int s = load_idx(ei, e, is64);
        int d = load_idx(ei, N_EDGES + e, is64);
        int pos = atomicAdd(&cursor[d], 1);
        cs_src[pos] = s;
        cs_w[pos] = nw[e];
    }
}

// ---------------------------------------------------------------------------
// Pull-based SpMM, one 64-lane wave per node, lane = feature. Fused Chebyshev
// recurrence: y = scale * sum_e w*v[src] + beta * prev.
__global__ __launch_bounds__(256) void spmm_pull(
    const int* __restrict__ row_ptr, const int* __restrict__ cs_src,
    const float* __restrict__ cs_w, const float* __restrict__ v,
    const float* __restrict__ prev, float* __restrict__ y, float scale,
    float beta) {
    int lane = threadIdx.x & 63;
    int node = (blockIdx.x << 2) + (threadIdx.x >> 6);
    int s0 = row_ptr[node];
    int s1 = row_ptr[node + 1];
    float acc = 0.f;
    int p = s0;
    for (; p + 3 < s1; p += 4) {
        int i0 = cs_src[p], i1 = cs_src[p + 1], i2 = cs_src[p + 2], i3 = cs_src[p + 3];
        float w0 = cs_w[p], w1 = cs_w[p + 1], w2 = cs_w[p + 2], w3 = cs_w[p + 3];
        float v0 = v[(size_t)i0 * FDIM + lane];
        float v1 = v[(size_t)i1 * FDIM + lane];
        float v2 = v[(size_t)i2 * FDIM + lane];
        float v3 = v[(size_t)i3 * FDIM + lane];
        acc = fmaf(w0, v0, acc);
        acc = fmaf(w1, v1, acc);
        acc = fmaf(w2, v2, acc);
        acc = fmaf(w3, v3, acc);
    }
    for (; p < s1; ++p)
        acc = fmaf(cs_w[p], v[(size_t)cs_src[p] * FDIM + lane], acc);
    size_t o = (size_t)node * FDIM + lane;
    float pv = (beta != 0.f) ? prev[o] : 0.f;
    y[o] = scale * acc + beta * pv;
}

// ---------------------------------------------------------------------------
__device__ __forceinline__ void fma4(float4& acc, float t, float4 wv) {
    acc.x = fmaf(t, wv.x, acc.x);
    acc.y = fmaf(t, wv.y, acc.y);
    acc.z = fmaf(t, wv.z, acc.z);
    acc.w = fmaf(t, wv.w, acc.w);
}

// Gate GEMM, LDS-staged. Block: 256 thr, 64 nodes, 256 out cols (128 z + 128 t
// interleaved in groups of 8). Thread (cg=tid&15, ng=tid>>4): 4 nodes x
// (8 z + 8 t) cols. K = 256 (4 cheb bases x 64 feats), tiles of 32.
__global__ __launch_bounds__(256) void gate_gemm2(
    const float* __restrict__ x, const float* __restrict__ tx1,
    const float* __restrict__ tx2, const float* __restrict__ tx3,
    const float* __restrict__ Wx, const float* __restrict__ bx,
    const float* __restrict__ bh, const float* __restrict__ Wlin,
    const float* __restrict__ blin, float* __restrict__ outv,
    float* __restrict__ logits) {
    __shared__ float At[32][68];   // [k][node], stride 68: 16B-aligned rows
    __shared__ float Ws[32][260];  // [k][256 interleaved cols], 1040B rows
    int tid = threadIdx.x;
    int cg = tid & 15;
    int ng = tid >> 4;
    long long nodeBase = (long long)blockIdx.x * 64;

    float4 accA[4], accB[4], accC[4], accD[4];
#pragma unroll
    for (int j = 0; j < 4; ++j) {
        accA[j] = make_float4(0.f, 0.f, 0.f, 0.f);
        accB[j] = make_float4(0.f, 0.f, 0.f, 0.f);
        accC[j] = make_float4(0.f, 0.f, 0.f, 0.f);
        accD[j] = make_float4(0.f, 0.f, 0.f, 0.f);
    }
    const float* Ts[4] = {x, tx1, tx2, tx3};

    for (int kt = 0; kt < 8; ++kt) {
        const float* srcA = Ts[kt >> 1];
        int foff = (kt & 1) * 32;
        {   // stage A transposed: node n = tid>>2, feats f0..f0+7
            int n = tid >> 2;
            int f0 = (tid & 3) * 8;
            const float* sp = srcA + (nodeBase + n) * FDIM + foff + f0;
            float4 v0 = *(const float4*)sp;
            float4 v1 = *(const float4*)(sp + 4);
            At[f0 + 0][n] = v0.x;
            At[f0 + 1][n] = v0.y;
            At[f0 + 2][n] = v0.z;
            At[f0 + 3][n] = v0.w;
            At[f0 + 4][n] = v1.x;
            At[f0 + 5][n] = v1.y;
            At[f0 + 6][n] = v1.z;
            At[f0 + 7][n] = v1.w;
        }
        // stage W: rows kk, cols interleaved [cg2: 8 z | 8 t]
#pragma unroll
        for (int r = 0; r < 8; ++r) {
            int s = r * 256 + tid;
            int kk = s >> 6;
            int q = s & 63;   // float4 slot in row
            int cg2 = q >> 2;
            int j4 = q & 3;
            int kg = kt * 32 + kk;
            const float* gsrc =
                (j4 < 2) ? Wx + (size_t)kg * HID + cg2 * 8 + j4 * 4
                         : Wx + (size_t)(512 + kg) * HID + cg2 * 8 + (j4 - 2) * 4;
            *(float4*)&Ws[kk][q * 4] = *(const float4*)gsrc;
        }
        __syncthreads();
        for (int kk = 0; kk < 32; ++kk) {
            float4 av = *(const float4*)&At[kk][ng * 4];
            const float* wr = &Ws[kk][cg * 16];
            float4 w0 = *(const float4*)(wr + 0);
            float4 w1 = *(const float4*)(wr + 4);
            float4 w2 = *(const float4*)(wr + 8);
            float4 w3 = *(const float4*)(wr + 12);
            float a[4] = {av.x, av.y, av.z, av.w};
#pragma unroll
            for (int j = 0; j < 4; ++j) {
                fma4(accA[j], a[j], w0);
                fma4(accB[j], a[j], w1);
                fma4(accC[j], a[j], w2);
                fma4(accD[j], a[j], w3);
            }
        }
        __syncthreads();
    }

    // epilogue: h = relu((1-sigmoid(z))*tanh(t)); reduce over 16 cg lanes/node
    int c0 = cg * 8;
    float bz[8], bt[8], wl[8];
#pragma unroll
    for (int q = 0; q < 8; ++q) {
        bz[q] = bx[c0 + q] + bh[c0 + q];
        bt[q] = bx[256 + c0 + q] + bh[256 + c0 + q];
        wl[q] = Wlin[c0 + q];
    }
#pragma unroll
    for (int j = 0; j < 4; ++j) {
        float zv[8] = {accA[j].x, accA[j].y, accA[j].z, accA[j].w,
                       accB[j].x, accB[j].y, accB[j].z, accB[j].w};
        float tv[8] = {accC[j].x, accC[j].y, accC[j].z, accC[j].w,
                       accD[j].x, accD[j].y, accD[j].z, accD[j].w};
        float sh = 0.f, shw = 0.f;
#pragma unroll
        for (int q = 0; q < 8; ++q) {
            float pz = zv[q] + bz[q];
            float pt = tv[q] + bt[q];
            float zg = 1.f / (1.f + __expf(-pz));
            float e2 = __expf(2.f * pt);
            float ht = 1.f - 2.f / (e2 + 1.f);
            float h = (1.f - zg) * ht;
            h = h > 0.f ? h : 0.f;
            sh += h;
            shw += h * wl[q];
        }
#pragma unroll
        for (int off = 8; off >= 1; off >>= 1) {
            sh += __shfl_xor(sh, off, 64);
            shw += __shfl_xor(shw, off, 64);
        }
        if (cg == 0) {
            long long node = nodeBase + ng * 4 + j;
            logits[node] = sqrtf(sh);
            outv[node] = shw + blin[0];
        }
    }
}

// ---------------------------------------------------------------------------
extern "C" void kernel_launch(void* const* d_in, const int* in_sizes, int n_in,
                              void* d_out, int out_size, void* d_ws, size_t ws_size,
                              hipStream_t stream) {
    const float* x = (const float*)d_in[0];
    const void* ei = d_in[1];
    const float* ew = (const float*)d_in[2];
    const float* Wx = (const float*)d_in[3];
    // d_in[4] = W_h unused (H=0 => cheb(H,..) = bias only); gate R fully dead.
    const float* bx = (const float*)d_in[5];
    const float* bh = (const float*)d_in[6];
    const float* Wlin = (const float*)d_in[7];
    const float* blin = (const float*)d_in[8];
    float* outv = (float*)d_out;
    float* logits = (float*)d_out + N_NODES;

    // workspace layout
    float* deg = (float*)d_ws;                    // N
    float* dinv = deg + N_NODES;                  // N
    int* flag = (int*)(dinv + N_NODES);           // 64
    int* cnt = flag + 64;                         // N
    int* row_ptr = cnt + N_NODES;                 // N + 64
    int* cursor = row_ptr + N_NODES + 64;         // N
    int* bsum = cursor + N_NODES;                 // 512
    int* boff = bsum + 512;                       // 512
    float* nw = (float*)(boff + 512);             // E
    int* cs_src = (int*)(nw + N_EDGES);           // E
    float* cs_w = (float*)(cs_src + N_EDGES);     // E
    float* tx1 = cs_w + N_EDGES;                  // N*64
    float* tx2 = tx1 + (size_t)N_NODES * FDIM;    // N*64
    float* tx3 = tx2 + (size_t)N_NODES * FDIM;    // N*64

    (void)hipMemsetAsync(deg, 0, N_NODES * sizeof(float), stream);
    (void)hipMemsetAsync(cnt, 0, N_NODES * sizeof(int), stream);
    detect_i64<<<1, 256, 0, stream>>>((const int*)ei, flag);
    deg_kernel<<<4096, 256, 0, stream>>>(ei, ew, deg, flag);
    dinv_kernel<<<N_NODES / 256, 256, 0, stream>>>(deg, dinv);
    prep_hist<<<4096, 256, 0, stream>>>(ei, ew, dinv, nw, cnt, flag);
    scan_block_sums<<<512, 256, 0, stream>>>(cnt, bsum);
    scan_bsums<<<1, 512, 0, stream>>>(bsum, boff, row_ptr);
    scan_final<<<512, 256, 0, stream>>>(cnt, boff, row_ptr, cursor);
    scatter_edges<<<4096, 256, 0, stream>>>(ei, nw, cursor, cs_src, cs_w, flag);

    spmm_pull<<<N_NODES / 4, 256, 0, stream>>>(row_ptr, cs_src, cs_w, x, x, tx1,
                                               1.f, 0.f);
    spmm_pull<<<N_NODES / 4, 256, 0, stream>>>(row_ptr, cs_src, cs_w, tx1, x, tx2,
                                               2.f, -1.f);
    spmm_pull<<<N_NODES / 4, 256, 0, stream>>>(row_ptr, cs_src, cs_w, tx2, tx1, tx3,
                                               2.f, -1.f);

    gate_gemm2<<<N_NODES / 64, 256, 0, stream>>>(x, tx1, tx2, tx3, Wx, bx, bh,
                                                 Wlin, blin, outv, logits);
}

// Round 4
// 1476.956 us; speedup vs baseline: 2.7057x; 1.1059x over previous
//
#include <hip/hip_runtime.h>

#define N_NODES 131072
#define N_EDGES 4194304
#define FDIM 64
#define HID 128

// ---------------------------------------------------------------------------
// Detect int64 vs int32 edge_index layout (JAX may deliver either).
__global__ void detect_i64(const int* __restrict__ ei, int* __restrict__ flag) {
    __shared__ int s_nz;
    int t = threadIdx.x;
    if (t == 0) s_nz = 0;
    __syncthreads();
    if (ei[2 * t + 1] != 0) atomicAdd(&s_nz, 1);
    __syncthreads();
    if (t == 0) *flag = (s_nz == 0) ? 1 : 0;
}

__device__ __forceinline__ int load_idx(const void* ei, long long pos, int is64) {
    if (is64) return (int)((const long long*)ei)[pos];
    return ((const int*)ei)[pos];
}

// ---------------------------------------------------------------------------
// ONE pass over edge_index: decode to int32 arrays, deg[src] += w, cnt[dst]++.
__global__ void decode_deg_hist(const void* __restrict__ ei, const float* __restrict__ w,
                                int* __restrict__ src32, int* __restrict__ dst32,
                                float* __restrict__ deg, int* __restrict__ cnt,
                                const int* __restrict__ flag) {
    int is64 = *flag;
    long long i = (long long)blockIdx.x * blockDim.x + threadIdx.x;
    long long stride = (long long)gridDim.x * blockDim.x;
    for (long long e = i; e < N_EDGES; e += stride) {
        int s = load_idx(ei, e, is64);
        int d = load_idx(ei, N_EDGES + e, is64);
        src32[e] = s;
        dst32[e] = d;
        atomicAdd(&deg[s], w[e]);
        atomicAdd(&cnt[d], 1);
    }
}

__global__ void dinv_kernel(const float* __restrict__ deg, float* __restrict__ dinv) {
    int i = blockIdx.x * blockDim.x + threadIdx.x;
    if (i < N_NODES) {
        float d = deg[i];
        dinv[i] = d > 0.f ? rsqrtf(d) : 0.f;
    }
}

// ---------------------------------------------------------------------------
// 3-kernel exclusive scan over cnt[N_NODES] -> row_ptr (+cursor copy)
__global__ void scan_block_sums(const int* __restrict__ cnt, int* __restrict__ bsum) {
    __shared__ int red[256];
    int i = blockIdx.x * 256 + threadIdx.x;
    red[threadIdx.x] = cnt[i];
    __syncthreads();
    for (int off = 128; off > 0; off >>= 1) {
        if (threadIdx.x < off) red[threadIdx.x] += red[threadIdx.x + off];
        __syncthreads();
    }
    if (threadIdx.x == 0) bsum[blockIdx.x] = red[0];
}

__global__ void scan_bsums(const int* __restrict__ bsum, int* __restrict__ boff,
                           int* __restrict__ row_ptr) {
    __shared__ int tmp[512];
    int t = threadIdx.x;
    tmp[t] = bsum[t];
    __syncthreads();
    for (int off = 1; off < 512; off <<= 1) {
        int v = (t >= off) ? tmp[t - off] : 0;
        __syncthreads();
        tmp[t] += v;
        __syncthreads();
    }
    boff[t] = tmp[t] - bsum[t];  // exclusive
    if (t == 0) row_ptr[N_NODES] = N_EDGES;
}

__global__ void scan_final(const int* __restrict__ cnt, const int* __restrict__ boff,
                           int* __restrict__ row_ptr, int* __restrict__ cursor) {
    __shared__ int tmp[256];
    int t = threadIdx.x;
    int i = blockIdx.x * 256 + t;
    int c = cnt[i];
    tmp[t] = c;
    __syncthreads();
    for (int off = 1; off < 256; off <<= 1) {
        int v = (t >= off) ? tmp[t - off] : 0;
        __syncthreads();
        tmp[t] += v;
        __syncthreads();
    }
    int excl = tmp[t] - c + boff[blockIdx.x];
    row_ptr[i] = excl;
    cursor[i] = excl;
}

// Counting-sort scatter: one packed 8B {src, w_bits} write per edge.
// nw computed on the fly from L2-resident dinv (512 KB).
__global__ void scatter_pack(const int* __restrict__ src32, const int* __restrict__ dst32,
                             const float* __restrict__ ew, const float* __restrict__ dinv,
                             int* __restrict__ cursor, int2* __restrict__ cs) {
    long long i = (long long)blockIdx.x * blockDim.x + threadIdx.x;
    long long stride = (long long)gridDim.x * blockDim.x;
    for (long long e = i; e < N_EDGES; e += stride) {
        int s = src32[e];
        int d = dst32[e];
        float w = -dinv[s] * ew[e] * dinv[d];
        int pos = atomicAdd(&cursor[d], 1);
        cs[pos] = make_int2(s, __float_as_int(w));
    }
}

// ---------------------------------------------------------------------------
// Pull-based SpMM, one 64-lane wave per node, lane = feature. Fused Chebyshev
// recurrence: y = scale * sum_e w*v[src] + beta * prev.
__global__ __launch_bounds__(256) void spmm_pull(
    const int* __restrict__ row_ptr, const int2* __restrict__ cs,
    const float* __restrict__ v, const float* __restrict__ prev,
    float* __restrict__ y, float scale, float beta) {
    int lane = threadIdx.x & 63;
    int node = (blockIdx.x << 2) + (threadIdx.x >> 6);
    int s0 = row_ptr[node];
    int s1 = row_ptr[node + 1];
    float acc = 0.f;
    int p = s0;
    for (; p + 3 < s1; p += 4) {
        int2 e0 = cs[p], e1 = cs[p + 1], e2 = cs[p + 2], e3 = cs[p + 3];
        float v0 = v[(size_t)e0.x * FDIM + lane];
        float v1 = v[(size_t)e1.x * FDIM + lane];
        float v2 = v[(size_t)e2.x * FDIM + lane];
        float v3 = v[(size_t)e3.x * FDIM + lane];
        acc = fmaf(__int_as_float(e0.y), v0, acc);
        acc = fmaf(__int_as_float(e1.y), v1, acc);
        acc = fmaf(__int_as_float(e2.y), v2, acc);
        acc = fmaf(__int_as_float(e3.y), v3, acc);
    }
    for (; p < s1; ++p) {
        int2 e0 = cs[p];
        acc = fmaf(__int_as_float(e0.y), v[(size_t)e0.x * FDIM + lane], acc);
    }
    size_t o = (size_t)node * FDIM + lane;
    float pv = (beta != 0.f) ? prev[o] : 0.f;
    y[o] = scale * acc + beta * pv;
}

// ---------------------------------------------------------------------------
__device__ __forceinline__ void fma4(float4& acc, float t, float4 wv) {
    acc.x = fmaf(t, wv.x, acc.x);
    acc.y = fmaf(t, wv.y, acc.y);
    acc.z = fmaf(t, wv.z, acc.z);
    acc.w = fmaf(t, wv.w, acc.w);
}

// Gate GEMM, LDS-staged. Block: 256 thr, 64 nodes, 256 out cols (128 z + 128 t
// interleaved in groups of 8). Thread (cg=tid&15, ng=tid>>4): 4 nodes x
// (8 z + 8 t) cols. K = 256 (4 cheb bases x 64 feats), tiles of 32.
__global__ __launch_bounds__(256) void gate_gemm2(
    const float* __restrict__ x, const float* __restrict__ tx1,
    const float* __restrict__ tx2, const float* __restrict__ tx3,
    const float* __restrict__ Wx, const float* __restrict__ bx,
    const float* __restrict__ bh, const float* __restrict__ Wlin,
    const float* __restrict__ blin, float* __restrict__ outv,
    float* __restrict__ logits) {
    __shared__ float At[32][68];   // [k][node]
    __shared__ float Ws[32][260];  // [k][256 interleaved cols]
    int tid = threadIdx.x;
    int cg = tid & 15;
    int ng = tid >> 4;
    long long nodeBase = (long long)blockIdx.x * 64;

    float4 accA[4], accB[4], accC[4], accD[4];
#pragma unroll
    for (int j = 0; j < 4; ++j) {
        accA[j] = make_float4(0.f, 0.f, 0.f, 0.f);
        accB[j] = make_float4(0.f, 0.f, 0.f, 0.f);
        accC[j] = make_float4(0.f, 0.f, 0.f, 0.f);
        accD[j] = make_float4(0.f, 0.f, 0.f, 0.f);
    }
    const float* Ts[4] = {x, tx1, tx2, tx3};

    for (int kt = 0; kt < 8; ++kt) {
        const float* srcA = Ts[kt >> 1];
        int foff = (kt & 1) * 32;
        {   // stage A transposed
            int n = tid >> 2;
            int f0 = (tid & 3) * 8;
            const float* sp = srcA + (nodeBase + n) * FDIM + foff + f0;
            float4 v0 = *(const float4*)sp;
            float4 v1 = *(const float4*)(sp + 4);
            At[f0 + 0][n] = v0.x;
            At[f0 + 1][n] = v0.y;
            At[f0 + 2][n] = v0.z;
            At[f0 + 3][n] = v0.w;
            At[f0 + 4][n] = v1.x;
            At[f0 + 5][n] = v1.y;
            At[f0 + 6][n] = v1.z;
            At[f0 + 7][n] = v1.w;
        }
#pragma unroll
        for (int r = 0; r < 8; ++r) {
            int s = r * 256 + tid;
            int kk = s >> 6;
            int q = s & 63;
            int cg2 = q >> 2;
            int j4 = q & 3;
            int kg = kt * 32 + kk;
            const float* gsrc =
                (j4 < 2) ? Wx + (size_t)kg * HID + cg2 * 8 + j4 * 4
                         : Wx + (size_t)(512 + kg) * HID + cg2 * 8 + (j4 - 2) * 4;
            *(float4*)&Ws[kk][q * 4] = *(const float4*)gsrc;
        }
        __syncthreads();
        for (int kk = 0; kk < 32; ++kk) {
            float4 av = *(const float4*)&At[kk][ng * 4];
            const float* wr = &Ws[kk][cg * 16];
            float4 w0 = *(const float4*)(wr + 0);
            float4 w1 = *(const float4*)(wr + 4);
            float4 w2 = *(const float4*)(wr + 8);
            float4 w3 = *(const float4*)(wr + 12);
            float a[4] = {av.x, av.y, av.z, av.w};
#pragma unroll
            for (int j = 0; j < 4; ++j) {
                fma4(accA[j], a[j], w0);
                fma4(accB[j], a[j], w1);
                fma4(accC[j], a[j], w2);
                fma4(accD[j], a[j], w3);
            }
        }
        __syncthreads();
    }

    int c0 = cg * 8;
    float bz[8], bt[8], wl[8];
#pragma unroll
    for (int q = 0; q < 8; ++q) {
        bz[q] = bx[c0 + q] + bh[c0 + q];
        bt[q] = bx[256 + c0 + q] + bh[256 + c0 + q];
        wl[q] = Wlin[c0 + q];
    }
#pragma unroll
    for (int j = 0; j < 4; ++j) {
        float zv[8] = {accA[j].x, accA[j].y, accA[j].z, accA[j].w,
                       accB[j].x, accB[j].y, accB[j].z, accB[j].w};
        float tv[8] = {accC[j].x, accC[j].y, accC[j].z, accC[j].w,
                       accD[j].x, accD[j].y, accD[j].z, accD[j].w};
        float sh = 0.f, shw = 0.f;
#pragma unroll
        for (int q = 0; q < 8; ++q) {
            float pz = zv[q] + bz[q];
            float pt = tv[q] + bt[q];
            float zg = 1.f / (1.f + __expf(-pz));
            float e2 = __expf(2.f * pt);
            float ht = 1.f - 2.f / (e2 + 1.f);
            float h = (1.f - zg) * ht;
            h = h > 0.f ? h : 0.f;
            sh += h;
            shw += h * wl[q];
        }
#pragma unroll
        for (int off = 8; off >= 1; off >>= 1) {
            sh += __shfl_xor(sh, off, 64);
            shw += __shfl_xor(shw, off, 64);
        }
        if (cg == 0) {
            long long node = nodeBase + ng * 4 + j;
            logits[node] = sqrtf(sh);
            outv[node] = shw + blin[0];
        }
    }
}

// ---------------------------------------------------------------------------
extern "C" void kernel_launch(void* const* d_in, const int* in_sizes, int n_in,
                              void* d_out, int out_size, void* d_ws, size_t ws_size,
                              hipStream_t stream) {
    const float* x = (const float*)d_in[0];
    const void* ei = d_in[1];
    const float* ew = (const float*)d_in[2];
    const float* Wx = (const float*)d_in[3];
    // d_in[4] = W_h unused (H=0 => cheb(H,..) = bias only); gate R fully dead.
    const float* bx = (const float*)d_in[5];
    const float* bh = (const float*)d_in[6];
    const float* Wlin = (const float*)d_in[7];
    const float* blin = (const float*)d_in[8];
    float* outv = (float*)d_out;
    float* logits = (float*)d_out + N_NODES;

    // workspace layout (words). tx1 ALIASES src32/dst32 (dead after scatter;
    // 2E words == N*FDIM words exactly).
    float* deg = (float*)d_ws;                    // N
    float* dinv = deg + N_NODES;                  // N
    int* flag = (int*)(dinv + N_NODES);           // 64
    int* cnt = flag + 64;                         // N
    int* row_ptr = cnt + N_NODES;                 // N + 64
    int* cursor = row_ptr + N_NODES + 64;         // N
    int* bsum = cursor + N_NODES;                 // 512
    int* boff = bsum + 512;                       // 512
    int* src32 = boff + 512;                      // E
    int* dst32 = src32 + N_EDGES;                 // E
    int2* cs = (int2*)(dst32 + N_EDGES);          // E int2 (2E words)
    float* tx1 = (float*)src32;                   // N*64 == 2E (alias)
    float* tx2 = (float*)(cs + N_EDGES);          // N*64
    float* tx3 = tx2 + (size_t)N_NODES * FDIM;    // N*64

    (void)hipMemsetAsync(deg, 0, N_NODES * sizeof(float), stream);
    (void)hipMemsetAsync(cnt, 0, N_NODES * sizeof(int), stream);
    detect_i64<<<1, 256, 0, stream>>>((const int*)ei, flag);
    decode_deg_hist<<<4096, 256, 0, stream>>>(ei, ew, src32, dst32, deg, cnt, flag);
    dinv_kernel<<<N_NODES / 256, 256, 0, stream>>>(deg, dinv);
    scan_block_sums<<<512, 256, 0, stream>>>(cnt, bsum);
    scan_bsums<<<1, 512, 0, stream>>>(bsum, boff, row_ptr);
    scan_final<<<512, 256, 0, stream>>>(cnt, boff, row_ptr, cursor);
    scatter_pack<<<4096, 256, 0, stream>>>(src32, dst32, ew, dinv, cursor, cs);

    spmm_pull<<<N_NODES / 4, 256, 0, stream>>>(row_ptr, cs, x, x, tx1, 1.f, 0.f);
    spmm_pull<<<N_NODES / 4, 256, 0, stream>>>(row_ptr, cs, tx1, x, tx2, 2.f, -1.f);
    spmm_pull<<<N_NODES / 4, 256, 0, stream>>>(row_ptr, cs, tx2, tx1, tx3, 2.f, -1.f);

    gate_gemm2<<<N_NODES / 64, 256, 0, stream>>>(x, tx1, tx2, tx3, Wx, bx, bh,
                                                 Wlin, blin, outv, logits);
}

// Round 11
// 1041.989 us; speedup vs baseline: 3.8352x; 1.4174x over previous
//
#include <hip/hip_runtime.h>
#include <hip/hip_fp16.h>

#define N_NODES 131072
#define N_EDGES 4194304
#define FDIM 64
#define HID 128
#define BPASS 512            // blocks in edge passes (A, C)
#define EPB (N_EDGES / BPASS)  // 8192 edges per block
#define K1 256               // coarse buckets (512 nodes each)

// ---------------------------------------------------------------------------
__global__ void detect_i64(const int* __restrict__ ei, int* __restrict__ flag) {
    __shared__ int s_nz;
    int t = threadIdx.x;
    if (t == 0) s_nz = 0;
    __syncthreads();
    if (ei[2 * t + 1] != 0) atomicAdd(&s_nz, 1);
    __syncthreads();
    if (t == 0) *flag = (s_nz == 0) ? 1 : 0;
}

__device__ __forceinline__ int load_idx(const void* ei, long long pos, int is64) {
    if (is64) return (int)((const long long*)ei)[pos];
    return ((const int*)ei)[pos];
}

// ---------------------------------------------------------------------------
// Pass A: per-block coarse histograms (dst>>9 and src>>9). No global atomics.
__global__ __launch_bounds__(256) void passA(const void* __restrict__ ei,
                                             const int* __restrict__ flag,
                                             int* __restrict__ hist_d,
                                             int* __restrict__ hist_s) {
    __shared__ int hd[K1], hs[K1];
    int t = threadIdx.x, b = blockIdx.x;
    hd[t] = 0;
    hs[t] = 0;
    __syncthreads();
    int is64 = *flag;
    long long base = (long long)b * EPB;
    for (int it = 0; it < EPB / 256; ++it) {
        long long e = base + it * 256 + t;
        int s = load_idx(ei, e, is64);
        int d = load_idx(ei, N_EDGES + e, is64);
        atomicAdd(&hd[d >> 9], 1);
        atomicAdd(&hs[s >> 9], 1);
    }
    __syncthreads();
    hist_d[b * K1 + t] = hd[t];
    hist_s[b * K1 + t] = hs[t];
}

// S1: column sums. Block j<256: dst column j; else src column j-256.
__global__ void s1_colsum(const int* __restrict__ hist_d, const int* __restrict__ hist_s,
                          int* __restrict__ colsum) {
    int j = blockIdx.x;
    const int* h = (j < K1) ? hist_d : hist_s;
    int col = j & (K1 - 1);
    __shared__ int red[256];
    int t = threadIdx.x;
    red[t] = h[t * K1 + col] + h[(t + 256) * K1 + col];
    __syncthreads();
    for (int off = 128; off > 0; off >>= 1) {
        if (t < off) red[t] += red[t + off];
        __syncthreads();
    }
    if (t == 0) colsum[j] = red[0];
}

// S2: exclusive scans of the two 256-entry colsum halves -> gbase (edge units).
// gbase[0..256] = dst bucket bases; gbase[257..513] = src bucket bases.
__global__ void s2_scan(const int* __restrict__ colsum, int* __restrict__ gbase) {
    __shared__ int tmp[256];
    int t = threadIdx.x;
    tmp[t] = colsum[t];
    __syncthreads();
    for (int off = 1; off < 256; off <<= 1) {
        int v = (t >= off) ? tmp[t - off] : 0;
        __syncthreads();
        tmp[t] += v;
        __syncthreads();
    }
    gbase[t] = tmp[t] - colsum[t];
    if (t == 255) gbase[256] = tmp[255];
    __syncthreads();
    tmp[t] = colsum[256 + t];
    __syncthreads();
    for (int off = 1; off < 256; off <<= 1) {
        int v = (t >= off) ? tmp[t - off] : 0;
        __syncthreads();
        tmp[t] += v;
        __syncthreads();
    }
    gbase[257 + t] = tmp[t] - colsum[256 + t];
    if (t == 255) gbase[513] = tmp[255];
}

// S3: per-bucket column scan over blocks -> per-(block,bucket) reservations.
__global__ void s3_off2(const int* __restrict__ hist_d, const int* __restrict__ hist_s,
                        const int* __restrict__ gbase, int* __restrict__ off2_d,
                        int* __restrict__ off2_s) {
    int j = blockIdx.x;
    const int* h = (j < K1) ? hist_d : hist_s;
    int* off2 = (j < K1) ? off2_d : off2_s;
    int col = j & (K1 - 1);
    int base = (j < K1) ? gbase[col] : gbase[257 + col];
    __shared__ int tpre[256];
    int t = threadIdx.x;
    int v0 = h[(2 * t) * K1 + col];
    int v1 = h[(2 * t + 1) * K1 + col];
    tpre[t] = v0 + v1;
    __syncthreads();
    for (int off = 1; off < 256; off <<= 1) {
        int v = (t >= off) ? tpre[t - off] : 0;
        __syncthreads();
        tpre[t] += v;
        __syncthreads();
    }
    int excl = tpre[t] - (v0 + v1);
    off2[(2 * t) * K1 + col] = base + excl;
    off2[(2 * t + 1) * K1 + col] = base + excl + v0;
}

// Pass C: scatter edges into reserved coarse-bucket chunks (chunk-contiguous
// writes -> L2 line combining). Emits dst-stream cs1 {(dl<<17)|src, w_bits}
// and src-stream sw1 {(sl<<23)|w_fix23}.
__global__ __launch_bounds__(256) void passC(const void* __restrict__ ei,
                                             const float* __restrict__ ew,
                                             const int* __restrict__ flag,
                                             const int* __restrict__ off2_d,
                                             const int* __restrict__ off2_s,
                                             int2* __restrict__ cs1,
                                             unsigned* __restrict__ sw1) {
    __shared__ int curD[K1], curS[K1];
    int t = threadIdx.x, b = blockIdx.x;
    curD[t] = off2_d[b * K1 + t];
    curS[t] = off2_s[b * K1 + t];
    __syncthreads();
    int is64 = *flag;
    long long base = (long long)b * EPB;
    for (int it = 0; it < EPB / 256; ++it) {
        long long e = base + it * 256 + t;
        int s = load_idx(ei, e, is64);
        int d = load_idx(ei, N_EDGES + e, is64);
        float w = ew[e];
        int pd = atomicAdd(&curD[d >> 9], 1);
        cs1[pd] = make_int2(((d & 511) << 17) | s, __float_as_int(w));
        unsigned wq = (unsigned)(w * 8388608.f);
        if (wq > 8388607u) wq = 8388607u;
        int ps = atomicAdd(&curS[s >> 9], 1);
        sw1[ps] = ((unsigned)(s & 511) << 23) | wq;
    }
}

// Pass D': per-src-bucket LDS reduction -> deg -> dinv. No global atomics.
__global__ __launch_bounds__(256) void passDp(const unsigned* __restrict__ sw1,
                                              const int* __restrict__ gbase,
                                              float* __restrict__ dinv) {
    __shared__ float acc[512];
    int k = blockIdx.x, t = threadIdx.x;
    acc[t] = 0.f;
    acc[t + 256] = 0.f;
    __syncthreads();
    int s0 = gbase[257 + k], s1 = gbase[257 + k + 1];
    for (int p = s0 + t; p < s1; p += 256) {
        unsigned v = sw1[p];
        atomicAdd(&acc[v >> 23], (float)(v & 8388607u) * (1.f / 8388608.f));
    }
    __syncthreads();
    for (int i = t; i < 512; i += 256) {
        float dg = acc[i];
        dinv[(k << 9) + i] = dg > 0.f ? rsqrtf(dg) : 0.f;
    }
}

// Pass D: local counting sort within each dst bucket -> final CSC cs2
// (packed (src<<15)|wq15) + row_ptr. All writes inside one 64KB block window.
__global__ __launch_bounds__(256) void passD(const int2* __restrict__ cs1,
                                             const int* __restrict__ gbase,
                                             unsigned* __restrict__ cs2,
                                             int* __restrict__ row_ptr) {
    __shared__ int hist[512], curs[512], tpre[256];
    int k = blockIdx.x, t = threadIdx.x;
    hist[t] = 0;
    hist[t + 256] = 0;
    __syncthreads();
    int s0 = gbase[k], s1 = gbase[k + 1];
    for (int p = s0 + t; p < s1; p += 256)
        atomicAdd(&hist[(unsigned)cs1[p].x >> 17], 1);
    __syncthreads();
    int v0 = hist[2 * t], v1 = hist[2 * t + 1];
    tpre[t] = v0 + v1;
    __syncthreads();
    for (int off = 1; off < 256; off <<= 1) {
        int v = (t >= off) ? tpre[t - off] : 0;
        __syncthreads();
        tpre[t] += v;
        __syncthreads();
    }
    int excl = tpre[t] - (v0 + v1);
    curs[2 * t] = excl;
    curs[2 * t + 1] = excl + v0;
    int nid = (k << 9) + 2 * t;
    row_ptr[nid] = s0 + excl;
    row_ptr[nid + 1] = s0 + excl + v0;
    if (k == K1 - 1 && t == 255) row_ptr[N_NODES] = N_EDGES;
    __syncthreads();
    for (int p = s0 + t; p < s1; p += 256) {
        int2 e = cs1[p];
        unsigned dl = (unsigned)e.x >> 17;
        int src = e.x & 0x1FFFF;
        float w = __int_as_float(e.y);
        unsigned wq = (unsigned)(w * 32768.f);
        if (wq > 32767u) wq = 32767u;
        int pos = s0 + atomicAdd(&curs[dl], 1);
        cs2[pos] = ((unsigned)src << 15) | wq;
    }
}

// ---------------------------------------------------------------------------
// x16 = f16(dinv .* x)   (the "v-tilde" for the first spmm)
__global__ void xscale16(const float* __restrict__ x, const float* __restrict__ dinv,
                         __half* __restrict__ x16) {
    int i = blockIdx.x * 256 + threadIdx.x;
    x16[i] = __float2half(dinv[i >> 6] * x[i]);
}

// Pull SpMM with fp16 gathers. L = -D A D; acc = sum w_raw * vtilde[src];
// y = scale*(-dinv[d])*acc + beta*prev.  Optionally writes f32 y and/or f16
// (scaled by dinv for the next gather, or unscaled for the gate GEMM).
__global__ __launch_bounds__(256) void spmm_pull16(
    const int* __restrict__ row_ptr, const unsigned* __restrict__ cs,
    const __half* __restrict__ v16, const float* __restrict__ prev,
    const float* __restrict__ dinv, float* __restrict__ y32,
    __half* __restrict__ y16, float scale, float beta, int scaled16) {
    int lane = threadIdx.x & 63;
    int node = (blockIdx.x << 2) + (threadIdx.x >> 6);
    int s0 = row_ptr[node];
    int s1 = row_ptr[node + 1];
    float acc = 0.f;
    int p = s0;
    for (; p + 3 < s1; p += 4) {
        unsigned e0 = cs[p], e1 = cs[p + 1], e2 = cs[p + 2], e3 = cs[p + 3];
        float v0 = __half2float(v16[(size_t)(e0 >> 15) * FDIM + lane]);
        float v1 = __half2float(v16[(size_t)(e1 >> 15) * FDIM + lane]);
        float v2 = __half2float(v16[(size_t)(e2 >> 15) * FDIM + lane]);
        float v3 = __half2float(v16[(size_t)(e3 >> 15) * FDIM + lane]);
        acc = fmaf(((e0 & 32767u) + 0.5f) * (1.f / 32768.f), v0, acc);
        acc = fmaf(((e1 & 32767u) + 0.5f) * (1.f / 32768.f), v1, acc);
        acc = fmaf(((e2 & 32767u) + 0.5f) * (1.f / 32768.f), v2, acc);
        acc = fmaf(((e3 & 32767u) + 0.5f) * (1.f / 32768.f), v3, acc);
    }
    for (; p < s1; ++p) {
        unsigned e0 = cs[p];
        acc = fmaf(((e0 & 32767u) + 0.5f) * (1.f / 32768.f),
                   __half2float(v16[(size_t)(e0 >> 15) * FDIM + lane]), acc);
    }
    size_t o = (size_t)node * FDIM + lane;
    float di = dinv[node];
    float y = scale * (-di) * acc;
    if (beta != 0.f) y += beta * prev[o];
    if (y32) y32[o] = y;
    if (y16) y16[o] = __float2half(scaled16 ? di * y : y);
}

// ---------------------------------------------------------------------------
__device__ __forceinline__ void fma4(float4& acc, float t, float4 wv) {
    acc.x = fmaf(t, wv.x, acc.x);
    acc.y = fmaf(t, wv.y, acc.y);
    acc.z = fmaf(t, wv.z, acc.z);
    acc.w = fmaf(t, wv.w, acc.w);
}

// Gate GEMM (z & h_tilde; R dead, W_h GEMMs zero since H=0). tx3 arrives f16.
__global__ __launch_bounds__(256) void gate_gemm2(
    const float* __restrict__ x, const float* __restrict__ tx1,
    const float* __restrict__ tx2, const __half* __restrict__ tx3h,
    const float* __restrict__ Wx, const float* __restrict__ bx,
    const float* __restrict__ bh, const float* __restrict__ Wlin,
    const float* __restrict__ blin, float* __restrict__ outv,
    float* __restrict__ logits) {
    __shared__ float At[32][68];
    __shared__ float Ws[32][260];
    int tid = threadIdx.x;
    int cg = tid & 15;
    int ng = tid >> 4;
    long long nodeBase = (long long)blockIdx.x * 64;

    float4 accA[4], accB[4], accC[4], accD[4];
#pragma unroll
    for (int j = 0; j < 4; ++j) {
        accA[j] = make_float4(0.f, 0.f, 0.f, 0.f);
        accB[j] = make_float4(0.f, 0.f, 0.f, 0.f);
        accC[j] = make_float4(0.f, 0.f, 0.f, 0.f);
        accD[j] = make_float4(0.f, 0.f, 0.f, 0.f);
    }
    const float* Ts[3] = {x, tx1, tx2};

    for (int kt = 0; kt < 8; ++kt) {
        int foff = (kt & 1) * 32;
        int n = tid >> 2;
        int f0 = (tid & 3) * 8;
        if (kt >= 6) {
            const __half* sp = tx3h + (nodeBase + n) * FDIM + foff + f0;
#pragma unroll
            for (int j = 0; j < 8; ++j) At[f0 + j][n] = __half2float(sp[j]);
        } else {
            const float* sp = Ts[kt >> 1] + (nodeBase + n) * FDIM + foff + f0;
            float4 v0 = *(const float4*)sp;
            float4 v1 = *(const float4*)(sp + 4);
            At[f0 + 0][n] = v0.x;
            At[f0 + 1][n] = v0.y;
            At[f0 + 2][n] = v0.z;
            At[f0 + 3][n] = v0.w;
            At[f0 + 4][n] = v1.x;
            At[f0 + 5][n] = v1.y;
            At[f0 + 6][n] = v1.z;
            At[f0 + 7][n] = v1.w;
        }
#pragma unroll
        for (int r = 0; r < 8; ++r) {
            int s = r * 256 + tid;
            int kk = s >> 6;
            int q = s & 63;
            int cg2 = q >> 2;
            int j4 = q & 3;
            int kg = kt * 32 + kk;
            const float* gsrc =
                (j4 < 2) ? Wx + (size_t)kg * HID + cg2 * 8 + j4 * 4
                         : Wx + (size_t)(512 + kg) * HID + cg2 * 8 + (j4 - 2) * 4;
            *(float4*)&Ws[kk][q * 4] = *(const float4*)gsrc;
        }
        __syncthreads();
        for (int kk = 0; kk < 32; ++kk) {
            float4 av = *(const float4*)&At[kk][ng * 4];
            const float* wr = &Ws[kk][cg * 16];
            float4 w0 = *(const float4*)(wr + 0);
            float4 w1 = *(const float4*)(wr + 4);
            float4 w2 = *(const float4*)(wr + 8);
            float4 w3 = *(const float4*)(wr + 12);
            float a[4] = {av.x, av.y, av.z, av.w};
#pragma unroll
            for (int j = 0; j < 4; ++j) {
                fma4(accA[j], a[j], w0);
                fma4(accB[j], a[j], w1);
                fma4(accC[j], a[j], w2);
                fma4(accD[j], a[j], w3);
            }
        }
        __syncthreads();
    }

    int c0 = cg * 8;
    float bz[8], bt[8], wl[8];
#pragma unroll
    for (int q = 0; q < 8; ++q) {
        bz[q] = bx[c0 + q] + bh[c0 + q];
        bt[q] = bx[256 + c0 + q] + bh[256 + c0 + q];
        wl[q] = Wlin[c0 + q];
    }
#pragma unroll
    for (int j = 0; j < 4; ++j) {
        float zv[8] = {accA[j].x, accA[j].y, accA[j].z, accA[j].w,
                       accB[j].x, accB[j].y, accB[j].z, accB[j].w};
        float tv[8] = {accC[j].x, accC[j].y, accC[j].z, accC[j].w,
                       accD[j].x, accD[j].y, accD[j].z, accD[j].w};
        float sh = 0.f, shw = 0.f;
#pragma unroll
        for (int q = 0; q < 8; ++q) {
            float pz = zv[q] + bz[q];
            float pt = tv[q] + bt[q];
            float zg = 1.f / (1.f + __expf(-pz));
            float e2 = __expf(2.f * pt);
            float ht = 1.f - 2.f / (e2 + 1.f);
            float h = (1.f - zg) * ht;
            h = h > 0.f ? h : 0.f;
            sh += h;
            shw += h * wl[q];
        }
#pragma unroll
        for (int off = 8; off >= 1; off >>= 1) {
            sh += __shfl_xor(sh, off, 64);
            shw += __shfl_xor(shw, off, 64);
        }
        if (cg == 0) {
            long long node = nodeBase + ng * 4 + j;
            logits[node] = sqrtf(sh);
            outv[node] = shw + blin[0];
        }
    }
}

// ---------------------------------------------------------------------------
extern "C" void kernel_launch(void* const* d_in, const int* in_sizes, int n_in,
                              void* d_out, int out_size, void* d_ws, size_t ws_size,
                              hipStream_t stream) {
    const float* x = (const float*)d_in[0];
    const void* ei = d_in[1];
    const float* ew = (const float*)d_in[2];
    const float* Wx = (const float*)d_in[3];
    const float* bx = (const float*)d_in[5];
    const float* bh = (const float*)d_in[6];
    const float* Wlin = (const float*)d_in[7];
    const float* blin = (const float*)d_in[8];
    float* outv = (float*)d_out;
    float* logits = (float*)d_out + N_NODES;

    // workspace (words); every buffer fully written before read -> no memsets
    float* dinv = (float*)d_ws;                         // N
    int* flag = (int*)(dinv + N_NODES);                 // 64
    int* row_ptr = flag + 64;                           // N + 64
    int* hist_d = row_ptr + N_NODES + 64;               // 512*256
    int* hist_s = hist_d + BPASS * K1;                  // 512*256
    int* off2_d = hist_s + BPASS * K1;                  // 512*256
    int* off2_s = off2_d + BPASS * K1;                  // 512*256
    int* colsum = off2_s + BPASS * K1;                  // 512
    int* gbase = colsum + 512;                          // 514 (pad 576)
    int2* cs1 = (int2*)(gbase + 576);                   // E int2   (32 MiB)
    unsigned* sw1 = (unsigned*)(cs1 + N_EDGES);         // E words  (16 MiB)
    unsigned* cs2 = sw1;                                // alias: sw1 dead after passDp
    float* tx1 = (float*)cs1;                           // alias: cs1 dead after passD
    float* tx2 = (float*)(sw1 + N_EDGES);               // N*64 f32 (32 MiB)
    __half* tx3h = (__half*)(tx2 + (size_t)N_NODES * FDIM);   // N*64 f16
    __half* x16 = tx3h + (size_t)N_NODES * FDIM;        // N*64 f16
    __half* t116 = x16 + (size_t)N_NODES * FDIM;        // N*64 f16
    __half* t216 = x16;                                 // alias: x16 dead after spmm1

    detect_i64<<<1, 256, 0, stream>>>((const int*)ei, flag);
    passA<<<BPASS, 256, 0, stream>>>(ei, flag, hist_d, hist_s);
    s1_colsum<<<512, 256, 0, stream>>>(hist_d, hist_s, colsum);
    s2_scan<<<1, 256, 0, stream>>>(colsum, gbase);
    s3_off2<<<512, 256, 0, stream>>>(hist_d, hist_s, gbase, off2_d, off2_s);
    passC<<<BPASS, 256, 0, stream>>>(ei, ew, flag, off2_d, off2_s, cs1, sw1);
    passDp<<<K1, 256, 0, stream>>>(sw1, gbase, dinv);
    passD<<<K1, 256, 0, stream>>>(cs1, gbase, cs2, row_ptr);
    xscale16<<<N_NODES * FDIM / 256, 256, 0, stream>>>(x, dinv, x16);

    // Tx1 = L x ; write f32 + scaled f16
    spmm_pull16<<<N_NODES / 4, 256, 0, stream>>>(row_ptr, cs2, x16, x, dinv,
                                                 tx1, t116, 1.f, 0.f, 1);
    // Tx2 = 2 L Tx1 - x
    spmm_pull16<<<N_NODES / 4, 256, 0, stream>>>(row_ptr, cs2, t116, x, dinv,
                                                 tx2, t216, 2.f, -1.f, 1);
    // Tx3 = 2 L Tx2 - Tx1 ; only f16 (unscaled) needed, for the gate GEMM
    spmm_pull16<<<N_NODES / 4, 256, 0, stream>>>(row_ptr, cs2, t216, tx1, dinv,
                                                 nullptr, tx3h, 2.f, -1.f, 0);

    gate_gemm2<<<N_NODES / 64, 256, 0, stream>>>(x, tx1, tx2, tx3h, Wx, bx, bh,
                                                 Wlin, blin, outv, logits);
}

// Round 12
// 955.971 us; speedup vs baseline: 4.1803x; 1.0900x over previous
//
#include <hip/hip_runtime.h>
#include <hip/hip_fp16.h>

#define N_NODES 131072
#define N_EDGES 4194304
#define FDIM 64
#define HID 128
#define BPASS 512            // blocks in edge passes (A, C)
#define EPB (N_EDGES / BPASS)  // 8192 edges per block
#define K1 256               // coarse buckets (512 nodes each)

// ---------------------------------------------------------------------------
__global__ void detect_i64(const int* __restrict__ ei, int* __restrict__ flag) {
    __shared__ int s_nz;
    int t = threadIdx.x;
    if (t == 0) s_nz = 0;
    __syncthreads();
    if (ei[2 * t + 1] != 0) atomicAdd(&s_nz, 1);
    __syncthreads();
    if (t == 0) *flag = (s_nz == 0) ? 1 : 0;
}

__device__ __forceinline__ int load_idx(const void* ei, long long pos, int is64) {
    if (is64) return (int)((const long long*)ei)[pos];
    return ((const int*)ei)[pos];
}

// ---------------------------------------------------------------------------
// Pass A: per-block coarse histograms (dst>>9 and src>>9). No global atomics.
__global__ __launch_bounds__(256) void passA(const void* __restrict__ ei,
                                             const int* __restrict__ flag,
                                             int* __restrict__ hist_d,
                                             int* __restrict__ hist_s) {
    __shared__ int hd[K1], hs[K1];
    int t = threadIdx.x, b = blockIdx.x;
    hd[t] = 0;
    hs[t] = 0;
    __syncthreads();
    int is64 = *flag;
    long long base = (long long)b * EPB;
    for (int it = 0; it < EPB / 256; ++it) {
        long long e = base + it * 256 + t;
        int s = load_idx(ei, e, is64);
        int d = load_idx(ei, N_EDGES + e, is64);
        atomicAdd(&hd[d >> 9], 1);
        atomicAdd(&hs[s >> 9], 1);
    }
    __syncthreads();
    hist_d[b * K1 + t] = hd[t];
    hist_s[b * K1 + t] = hs[t];
}

// S1: column sums. Block j<256: dst column j; else src column j-256.
__global__ void s1_colsum(const int* __restrict__ hist_d, const int* __restrict__ hist_s,
                          int* __restrict__ colsum) {
    int j = blockIdx.x;
    const int* h = (j < K1) ? hist_d : hist_s;
    int col = j & (K1 - 1);
    __shared__ int red[256];
    int t = threadIdx.x;
    red[t] = h[t * K1 + col] + h[(t + 256) * K1 + col];
    __syncthreads();
    for (int off = 128; off > 0; off >>= 1) {
        if (t < off) red[t] += red[t + off];
        __syncthreads();
    }
    if (t == 0) colsum[j] = red[0];
}

// S2: exclusive scans of the two 256-entry colsum halves -> gbase (edge units).
// gbase[0..256] = dst bucket bases; gbase[257..513] = src bucket bases.
__global__ void s2_scan(const int* __restrict__ colsum, int* __restrict__ gbase) {
    __shared__ int tmp[256];
    int t = threadIdx.x;
    tmp[t] = colsum[t];
    __syncthreads();
    for (int off = 1; off < 256; off <<= 1) {
        int v = (t >= off) ? tmp[t - off] : 0;
        __syncthreads();
        tmp[t] += v;
        __syncthreads();
    }
    gbase[t] = tmp[t] - colsum[t];
    if (t == 255) gbase[256] = tmp[255];
    __syncthreads();
    tmp[t] = colsum[256 + t];
    __syncthreads();
    for (int off = 1; off < 256; off <<= 1) {
        int v = (t >= off) ? tmp[t - off] : 0;
        __syncthreads();
        tmp[t] += v;
        __syncthreads();
    }
    gbase[257 + t] = tmp[t] - colsum[256 + t];
    if (t == 255) gbase[513] = tmp[255];
}

// S3: per-bucket column scan over blocks -> per-(block,bucket) reservations.
__global__ void s3_off2(const int* __restrict__ hist_d, const int* __restrict__ hist_s,
                        const int* __restrict__ gbase, int* __restrict__ off2_d,
                        int* __restrict__ off2_s) {
    int j = blockIdx.x;
    const int* h = (j < K1) ? hist_d : hist_s;
    int* off2 = (j < K1) ? off2_d : off2_s;
    int col = j & (K1 - 1);
    int base = (j < K1) ? gbase[col] : gbase[257 + col];
    __shared__ int tpre[256];
    int t = threadIdx.x;
    int v0 = h[(2 * t) * K1 + col];
    int v1 = h[(2 * t + 1) * K1 + col];
    tpre[t] = v0 + v1;
    __syncthreads();
    for (int off = 1; off < 256; off <<= 1) {
        int v = (t >= off) ? tpre[t - off] : 0;
        __syncthreads();
        tpre[t] += v;
        __syncthreads();
    }
    int excl = tpre[t] - (v0 + v1);
    off2[(2 * t) * K1 + col] = base + excl;
    off2[(2 * t + 1) * K1 + col] = base + excl + v0;
}

// Pass C: scatter edges into reserved coarse-bucket chunks (chunk-contiguous
// writes -> L2 line combining). Emits dst-stream cs1 {(dl<<17)|src, w_bits}
// and src-stream sw1 {(sl<<23)|w_fix23}.
__global__ __launch_bounds__(256) void passC(const void* __restrict__ ei,
                                             const float* __restrict__ ew,
                                             const int* __restrict__ flag,
                                             const int* __restrict__ off2_d,
                                             const int* __restrict__ off2_s,
                                             int2* __restrict__ cs1,
                                             unsigned* __restrict__ sw1) {
    __shared__ int curD[K1], curS[K1];
    int t = threadIdx.x, b = blockIdx.x;
    curD[t] = off2_d[b * K1 + t];
    curS[t] = off2_s[b * K1 + t];
    __syncthreads();
    int is64 = *flag;
    long long base = (long long)b * EPB;
    for (int it = 0; it < EPB / 256; ++it) {
        long long e = base + it * 256 + t;
        int s = load_idx(ei, e, is64);
        int d = load_idx(ei, N_EDGES + e, is64);
        float w = ew[e];
        int pd = atomicAdd(&curD[d >> 9], 1);
        cs1[pd] = make_int2(((d & 511) << 17) | s, __float_as_int(w));
        unsigned wq = (unsigned)(w * 8388608.f);
        if (wq > 8388607u) wq = 8388607u;
        int ps = atomicAdd(&curS[s >> 9], 1);
        sw1[ps] = ((unsigned)(s & 511) << 23) | wq;
    }
}

// Pass D': per-src-bucket LDS reduction -> deg -> dinv. No global atomics.
__global__ __launch_bounds__(256) void passDp(const unsigned* __restrict__ sw1,
                                              const int* __restrict__ gbase,
                                              float* __restrict__ dinv) {
    __shared__ float acc[512];
    int k = blockIdx.x, t = threadIdx.x;
    acc[t] = 0.f;
    acc[t + 256] = 0.f;
    __syncthreads();
    int s0 = gbase[257 + k], s1 = gbase[257 + k + 1];
    for (int p = s0 + t; p < s1; p += 256) {
        unsigned v = sw1[p];
        atomicAdd(&acc[v >> 23], (float)(v & 8388607u) * (1.f / 8388608.f));
    }
    __syncthreads();
    for (int i = t; i < 512; i += 256) {
        float dg = acc[i];
        dinv[(k << 9) + i] = dg > 0.f ? rsqrtf(dg) : 0.f;
    }
}

// Pass D: local counting sort within each dst bucket -> final CSC cs2
// (packed (src<<15)|wq15) + row_ptr. All writes inside one 64KB block window.
__global__ __launch_bounds__(256) void passD(const int2* __restrict__ cs1,
                                             const int* __restrict__ gbase,
                                             unsigned* __restrict__ cs2,
                                             int* __restrict__ row_ptr) {
    __shared__ int hist[512], curs[512], tpre[256];
    int k = blockIdx.x, t = threadIdx.x;
    hist[t] = 0;
    hist[t + 256] = 0;
    __syncthreads();
    int s0 = gbase[k], s1 = gbase[k + 1];
    for (int p = s0 + t; p < s1; p += 256)
        atomicAdd(&hist[(unsigned)cs1[p].x >> 17], 1);
    __syncthreads();
    int v0 = hist[2 * t], v1 = hist[2 * t + 1];
    tpre[t] = v0 + v1;
    __syncthreads();
    for (int off = 1; off < 256; off <<= 1) {
        int v = (t >= off) ? tpre[t - off] : 0;
        __syncthreads();
        tpre[t] += v;
        __syncthreads();
    }
    int excl = tpre[t] - (v0 + v1);
    curs[2 * t] = excl;
    curs[2 * t + 1] = excl + v0;
    int nid = (k << 9) + 2 * t;
    row_ptr[nid] = s0 + excl;
    row_ptr[nid + 1] = s0 + excl + v0;
    if (k == K1 - 1 && t == 255) row_ptr[N_NODES] = N_EDGES;
    __syncthreads();
    for (int p = s0 + t; p < s1; p += 256) {
        int2 e = cs1[p];
        unsigned dl = (unsigned)e.x >> 17;
        int src = e.x & 0x1FFFF;
        float w = __int_as_float(e.y);
        unsigned wq = (unsigned)(w * 32768.f);
        if (wq > 32767u) wq = 32767u;
        int pos = s0 + atomicAdd(&curs[dl], 1);
        cs2[pos] = ((unsigned)src << 15) | wq;
    }
}

// ---------------------------------------------------------------------------
// x16 = f16(dinv .* x)   (the "v-tilde" for the first spmm)
__global__ void xscale16(const float* __restrict__ x, const float* __restrict__ dinv,
                         __half* __restrict__ x16) {
    int i = blockIdx.x * 256 + threadIdx.x;
    x16[i] = __float2half(dinv[i >> 6] * x[i]);
}

// Pull SpMM with fp16 gathers. L = -D A D; acc = sum w_raw * vtilde[src];
// y = scale*(-dinv[d])*acc + beta*prev.  Optionally writes f32 y and/or f16
// (scaled by dinv for the next gather, or unscaled for the gate GEMM).
__global__ __launch_bounds__(256) void spmm_pull16(
    const int* __restrict__ row_ptr, const unsigned* __restrict__ cs,
    const __half* __restrict__ v16, const float* __restrict__ prev,
    const float* __restrict__ dinv, float* __restrict__ y32,
    __half* __restrict__ y16, float scale, float beta, int scaled16) {
    int lane = threadIdx.x & 63;
    int node = (blockIdx.x << 2) + (threadIdx.x >> 6);
    int s0 = row_ptr[node];
    int s1 = row_ptr[node + 1];
    float acc = 0.f;
    int p = s0;
    for (; p + 3 < s1; p += 4) {
        unsigned e0 = cs[p], e1 = cs[p + 1], e2 = cs[p + 2], e3 = cs[p + 3];
        float v0 = __half2float(v16[(size_t)(e0 >> 15) * FDIM + lane]);
        float v1 = __half2float(v16[(size_t)(e1 >> 15) * FDIM + lane]);
        float v2 = __half2float(v16[(size_t)(e2 >> 15) * FDIM + lane]);
        float v3 = __half2float(v16[(size_t)(e3 >> 15) * FDIM + lane]);
        acc = fmaf(((e0 & 32767u) + 0.5f) * (1.f / 32768.f), v0, acc);
        acc = fmaf(((e1 & 32767u) + 0.5f) * (1.f / 32768.f), v1, acc);
        acc = fmaf(((e2 & 32767u) + 0.5f) * (1.f / 32768.f), v2, acc);
        acc = fmaf(((e3 & 32767u) + 0.5f) * (1.f / 32768.f), v3, acc);
    }
    for (; p < s1; ++p) {
        unsigned e0 = cs[p];
        acc = fmaf(((e0 & 32767u) + 0.5f) * (1.f / 32768.f),
                   __half2float(v16[(size_t)(e0 >> 15) * FDIM + lane]), acc);
    }
    size_t o = (size_t)node * FDIM + lane;
    float di = dinv[node];
    float y = scale * (-di) * acc;
    if (beta != 0.f) y += beta * prev[o];
    if (y32) y32[o] = y;
    if (y16) y16[o] = __float2half(scaled16 ? di * y : y);
}

// ---------------------------------------------------------------------------
__device__ __forceinline__ void fma4(float4& acc, float t, float4 wv) {
    acc.x = fmaf(t, wv.x, acc.x);
    acc.y = fmaf(t, wv.y, acc.y);
    acc.z = fmaf(t, wv.z, acc.z);
    acc.w = fmaf(t, wv.w, acc.w);
}

// Gate GEMM (z & h_tilde; R dead, W_h GEMMs zero since H=0). tx3 arrives f16.
// Ws physical layout TRANSPOSED vs round-11: logical (cg2, j4) lives at
// 16B-slot p = j4*16 + cg2. Reads: lane cg's 4 float4s at word offsets
// {0,64,128,192} + cg*4 -> banks (cg*4)&31 spread over 8 groups, 2-way = free
// (was cg*16 -> 2 groups, 8-way, 1.04e8 conflicts). Writes: lane l writes
// phys slot l -> consecutive 16B, conflict-free; global side reads two
// contiguous 512B weight rows per wave.
__global__ __launch_bounds__(256) void gate_gemm2(
    const float* __restrict__ x, const float* __restrict__ tx1,
    const float* __restrict__ tx2, const __half* __restrict__ tx3h,
    const float* __restrict__ Wx, const float* __restrict__ bx,
    const float* __restrict__ bh, const float* __restrict__ Wlin,
    const float* __restrict__ blin, float* __restrict__ outv,
    float* __restrict__ logits) {
    __shared__ float At[32][68];
    __shared__ float Ws[32][260];
    int tid = threadIdx.x;
    int cg = tid & 15;
    int ng = tid >> 4;
    long long nodeBase = (long long)blockIdx.x * 64;

    float4 accA[4], accB[4], accC[4], accD[4];
#pragma unroll
    for (int j = 0; j < 4; ++j) {
        accA[j] = make_float4(0.f, 0.f, 0.f, 0.f);
        accB[j] = make_float4(0.f, 0.f, 0.f, 0.f);
        accC[j] = make_float4(0.f, 0.f, 0.f, 0.f);
        accD[j] = make_float4(0.f, 0.f, 0.f, 0.f);
    }
    const float* Ts[3] = {x, tx1, tx2};

    for (int kt = 0; kt < 8; ++kt) {
        int foff = (kt & 1) * 32;
        int n = tid >> 2;
        int f0 = (tid & 3) * 8;
        if (kt >= 6) {
            const __half* sp = tx3h + (nodeBase + n) * FDIM + foff + f0;
#pragma unroll
            for (int j = 0; j < 8; ++j) At[f0 + j][n] = __half2float(sp[j]);
        } else {
            const float* sp = Ts[kt >> 1] + (nodeBase + n) * FDIM + foff + f0;
            float4 v0 = *(const float4*)sp;
            float4 v1 = *(const float4*)(sp + 4);
            At[f0 + 0][n] = v0.x;
            At[f0 + 1][n] = v0.y;
            At[f0 + 2][n] = v0.z;
            At[f0 + 3][n] = v0.w;
            At[f0 + 4][n] = v1.x;
            At[f0 + 5][n] = v1.y;
            At[f0 + 6][n] = v1.z;
            At[f0 + 7][n] = v1.w;
        }
        // stage W: lane writes phys 16B-slot p = tid&63 of row kk.
        // p = j4*16 + cg2 -> j4 = p>>4 (0,1: z halves; 2,3: t halves),
        // cg2 = p&15. Source col = cg2*8 + (j4&1)*4 of gate row.
#pragma unroll
        for (int r = 0; r < 8; ++r) {
            int s = r * 256 + tid;
            int kk = s >> 6;
            int p = s & 63;
            int j4 = p >> 4;
            int cg2 = p & 15;
            int kg = kt * 32 + kk;
            const float* gsrc =
                (j4 < 2) ? Wx + (size_t)kg * HID + cg2 * 8 + j4 * 4
                         : Wx + (size_t)(512 + kg) * HID + cg2 * 8 + (j4 - 2) * 4;
            *(float4*)&Ws[kk][p * 4] = *(const float4*)gsrc;
        }
        __syncthreads();
        for (int kk = 0; kk < 32; ++kk) {
            float4 av = *(const float4*)&At[kk][ng * 4];
            const float* wr = &Ws[kk][0];
            float4 w0 = *(const float4*)(wr + cg * 4);          // z cols cg*8+0..3
            float4 w1 = *(const float4*)(wr + 64 + cg * 4);     // z cols cg*8+4..7
            float4 w2 = *(const float4*)(wr + 128 + cg * 4);    // t cols cg*8+0..3
            float4 w3 = *(const float4*)(wr + 192 + cg * 4);    // t cols cg*8+4..7
            float a[4] = {av.x, av.y, av.z, av.w};
#pragma unroll
            for (int j = 0; j < 4; ++j) {
                fma4(accA[j], a[j], w0);
                fma4(accB[j], a[j], w1);
                fma4(accC[j], a[j], w2);
                fma4(accD[j], a[j], w3);
            }
        }
        __syncthreads();
    }

    int c0 = cg * 8;
    float bz[8], bt[8], wl[8];
#pragma unroll
    for (int q = 0; q < 8; ++q) {
        bz[q] = bx[c0 + q] + bh[c0 + q];
        bt[q] = bx[256 + c0 + q] + bh[256 + c0 + q];
        wl[q] = Wlin[c0 + q];
    }
#pragma unroll
    for (int j = 0; j < 4; ++j) {
        float zv[8] = {accA[j].x, accA[j].y, accA[j].z, accA[j].w,
                       accB[j].x, accB[j].y, accB[j].z, accB[j].w};
        float tv[8] = {accC[j].x, accC[j].y, accC[j].z, accC[j].w,
                       accD[j].x, accD[j].y, accD[j].z, accD[j].w};
        float sh = 0.f, shw = 0.f;
#pragma unroll
        for (int q = 0; q < 8; ++q) {
            float pz = zv[q] + bz[q];
            float pt = tv[q] + bt[q];
            float zg = 1.f / (1.f + __expf(-pz));
            float e2 = __expf(2.f * pt);
            float ht = 1.f - 2.f / (e2 + 1.f);
            float h = (1.f - zg) * ht;
            h = h > 0.f ? h : 0.f;
            sh += h;
            shw += h * wl[q];
        }
#pragma unroll
        for (int off = 8; off >= 1; off >>= 1) {
            sh += __shfl_xor(sh, off, 64);
            shw += __shfl_xor(shw, off, 64);
        }
        if (cg == 0) {
            long long node = nodeBase + ng * 4 + j;
            logits[node] = sqrtf(sh);
            outv[node] = shw + blin[0];
        }
    }
}

// ---------------------------------------------------------------------------
extern "C" void kernel_launch(void* const* d_in, const int* in_sizes, int n_in,
                              void* d_out, int out_size, void* d_ws, size_t ws_size,
                              hipStream_t stream) {
    const float* x = (const float*)d_in[0];
    const void* ei = d_in[1];
    const float* ew = (const float*)d_in[2];
    const float* Wx = (const float*)d_in[3];
    const float* bx = (const float*)d_in[5];
    const float* bh = (const float*)d_in[6];
    const float* Wlin = (const float*)d_in[7];
    const float* blin = (const float*)d_in[8];
    float* outv = (float*)d_out;
    float* logits = (float*)d_out + N_NODES;

    // workspace (words); every buffer fully written before read -> no memsets
    float* dinv = (float*)d_ws;                         // N
    int* flag = (int*)(dinv + N_NODES);                 // 64
    int* row_ptr = flag + 64;                           // N + 64
    int* hist_d = row_ptr + N_NODES + 64;               // 512*256
    int* hist_s = hist_d + BPASS * K1;                  // 512*256
    int* off2_d = hist_s + BPASS * K1;                  // 512*256
    int* off2_s = off2_d + BPASS * K1;                  // 512*256
    int* colsum = off2_s + BPASS * K1;                  // 512
    int* gbase = colsum + 512;                          // 514 (pad 576)
    int2* cs1 = (int2*)(gbase + 576);                   // E int2   (32 MiB)
    unsigned* sw1 = (unsigned*)(cs1 + N_EDGES);         // E words  (16 MiB)
    unsigned* cs2 = sw1;                                // alias: sw1 dead after passDp
    float* tx1 = (float*)cs1;                           // alias: cs1 dead after passD
    float* tx2 = (float*)(sw1 + N_EDGES);               // N*64 f32 (32 MiB)
    __half* tx3h = (__half*)(tx2 + (size_t)N_NODES * FDIM);   // N*64 f16
    __half* x16 = tx3h + (size_t)N_NODES * FDIM;        // N*64 f16
    __half* t116 = x16 + (size_t)N_NODES * FDIM;        // N*64 f16
    __half* t216 = x16;                                 // alias: x16 dead after spmm1

    detect_i64<<<1, 256, 0, stream>>>((const int*)ei, flag);
    passA<<<BPASS, 256, 0, stream>>>(ei, flag, hist_d, hist_s);
    s1_colsum<<<512, 256, 0, stream>>>(hist_d, hist_s, colsum);
    s2_scan<<<1, 256, 0, stream>>>(colsum, gbase);
    s3_off2<<<512, 256, 0, stream>>>(hist_d, hist_s, gbase, off2_d, off2_s);
    passC<<<BPASS, 256, 0, stream>>>(ei, ew, flag, off2_d, off2_s, cs1, sw1);
    passDp<<<K1, 256, 0, stream>>>(sw1, gbase, dinv);
    passD<<<K1, 256, 0, stream>>>(cs1, gbase, cs2, row_ptr);
    xscale16<<<N_NODES * FDIM / 256, 256, 0, stream>>>(x, dinv, x16);

    // Tx1 = L x ; write f32 + scaled f16
    spmm_pull16<<<N_NODES / 4, 256, 0, stream>>>(row_ptr, cs2, x16, x, dinv,
                                                 tx1, t116, 1.f, 0.f, 1);
    // Tx2 = 2 L Tx1 - x
    spmm_pull16<<<N_NODES / 4, 256, 0, stream>>>(row_ptr, cs2, t116, x, dinv,
                                                 tx2, t216, 2.f, -1.f, 1);
    // Tx3 = 2 L Tx2 - Tx1 ; only f16 (unscaled) needed, for the gate GEMM
    spmm_pull16<<<N_NODES / 4, 256, 0, stream>>>(row_ptr, cs2, t216, tx1, dinv,
                                                 nullptr, tx3h, 2.f, -1.f, 0);

    gate_gemm2<<<N_NODES / 64, 256, 0, stream>>>(x, tx1, tx2, tx3h, Wx, bx, bh,
                                                 Wlin, blin, outv, logits);
}

// Round 13
// 809.483 us; speedup vs baseline: 4.9368x; 1.1810x over previous
//
#include <hip/hip_runtime.h>
#include <hip/hip_fp16.h>

#define N_NODES 131072
#define N_EDGES 4194304
#define FDIM 64
#define HID 128
#define BPASS 512            // blocks in edge passes (A, C)
#define EPB (N_EDGES / BPASS)  // 8192 edges per block
#define K1 256               // coarse buckets (512 nodes each)

typedef _Float16 f16x8 __attribute__((ext_vector_type(8)));
typedef float f32x4 __attribute__((ext_vector_type(4)));

// ---------------------------------------------------------------------------
__global__ void detect_i64(const int* __restrict__ ei, int* __restrict__ flag) {
    __shared__ int s_nz;
    int t = threadIdx.x;
    if (t == 0) s_nz = 0;
    __syncthreads();
    if (ei[2 * t + 1] != 0) atomicAdd(&s_nz, 1);
    __syncthreads();
    if (t == 0) *flag = (s_nz == 0) ? 1 : 0;
}

__device__ __forceinline__ int load_idx(const void* ei, long long pos, int is64) {
    if (is64) return (int)((const long long*)ei)[pos];
    return ((const int*)ei)[pos];
}

// ---------------------------------------------------------------------------
// Pass A: per-block coarse histograms (dst>>9 and src>>9). No global atomics.
__global__ __launch_bounds__(256) void passA(const void* __restrict__ ei,
                                             const int* __restrict__ flag,
                                             int* __restrict__ hist_d,
                                             int* __restrict__ hist_s) {
    __shared__ int hd[K1], hs[K1];
    int t = threadIdx.x, b = blockIdx.x;
    hd[t] = 0;
    hs[t] = 0;
    __syncthreads();
    int is64 = *flag;
    long long base = (long long)b * EPB;
    for (int it = 0; it < EPB / 256; ++it) {
        long long e = base + it * 256 + t;
        int s = load_idx(ei, e, is64);
        int d = load_idx(ei, N_EDGES + e, is64);
        atomicAdd(&hd[d >> 9], 1);
        atomicAdd(&hs[s >> 9], 1);
    }
    __syncthreads();
    hist_d[b * K1 + t] = hd[t];
    hist_s[b * K1 + t] = hs[t];
}

// S1: column sums. Block j<256: dst column j; else src column j-256.
__global__ void s1_colsum(const int* __restrict__ hist_d, const int* __restrict__ hist_s,
                          int* __restrict__ colsum) {
    int j = blockIdx.x;
    const int* h = (j < K1) ? hist_d : hist_s;
    int col = j & (K1 - 1);
    __shared__ int red[256];
    int t = threadIdx.x;
    red[t] = h[t * K1 + col] + h[(t + 256) * K1 + col];
    __syncthreads();
    for (int off = 128; off > 0; off >>= 1) {
        if (t < off) red[t] += red[t + off];
        __syncthreads();
    }
    if (t == 0) colsum[j] = red[0];
}

// S2: exclusive scans of the two 256-entry colsum halves -> gbase (edge units).
__global__ void s2_scan(const int* __restrict__ colsum, int* __restrict__ gbase) {
    __shared__ int tmp[256];
    int t = threadIdx.x;
    tmp[t] = colsum[t];
    __syncthreads();
    for (int off = 1; off < 256; off <<= 1) {
        int v = (t >= off) ? tmp[t - off] : 0;
        __syncthreads();
        tmp[t] += v;
        __syncthreads();
    }
    gbase[t] = tmp[t] - colsum[t];
    if (t == 255) gbase[256] = tmp[255];
    __syncthreads();
    tmp[t] = colsum[256 + t];
    __syncthreads();
    for (int off = 1; off < 256; off <<= 1) {
        int v = (t >= off) ? tmp[t - off] : 0;
        __syncthreads();
        tmp[t] += v;
        __syncthreads();
    }
    gbase[257 + t] = tmp[t] - colsum[256 + t];
    if (t == 255) gbase[513] = tmp[255];
}

// S3: per-bucket column scan over blocks -> per-(block,bucket) reservations.
__global__ void s3_off2(const int* __restrict__ hist_d, const int* __restrict__ hist_s,
                        const int* __restrict__ gbase, int* __restrict__ off2_d,
                        int* __restrict__ off2_s) {
    int j = blockIdx.x;
    const int* h = (j < K1) ? hist_d : hist_s;
    int* off2 = (j < K1) ? off2_d : off2_s;
    int col = j & (K1 - 1);
    int base = (j < K1) ? gbase[col] : gbase[257 + col];
    __shared__ int tpre[256];
    int t = threadIdx.x;
    int v0 = h[(2 * t) * K1 + col];
    int v1 = h[(2 * t + 1) * K1 + col];
    tpre[t] = v0 + v1;
    __syncthreads();
    for (int off = 1; off < 256; off <<= 1) {
        int v = (t >= off) ? tpre[t - off] : 0;
        __syncthreads();
        tpre[t] += v;
        __syncthreads();
    }
    int excl = tpre[t] - (v0 + v1);
    off2[(2 * t) * K1 + col] = base + excl;
    off2[(2 * t + 1) * K1 + col] = base + excl + v0;
}

// Pass C: scatter edges into reserved coarse-bucket chunks.
__global__ __launch_bounds__(256) void passC(const void* __restrict__ ei,
                                             const float* __restrict__ ew,
                                             const int* __restrict__ flag,
                                             const int* __restrict__ off2_d,
                                             const int* __restrict__ off2_s,
                                             int2* __restrict__ cs1,
                                             unsigned* __restrict__ sw1) {
    __shared__ int curD[K1], curS[K1];
    int t = threadIdx.x, b = blockIdx.x;
    curD[t] = off2_d[b * K1 + t];
    curS[t] = off2_s[b * K1 + t];
    __syncthreads();
    int is64 = *flag;
    long long base = (long long)b * EPB;
    for (int it = 0; it < EPB / 256; ++it) {
        long long e = base + it * 256 + t;
        int s = load_idx(ei, e, is64);
        int d = load_idx(ei, N_EDGES + e, is64);
        float w = ew[e];
        int pd = atomicAdd(&curD[d >> 9], 1);
        cs1[pd] = make_int2(((d & 511) << 17) | s, __float_as_int(w));
        unsigned wq = (unsigned)(w * 8388608.f);
        if (wq > 8388607u) wq = 8388607u;
        int ps = atomicAdd(&curS[s >> 9], 1);
        sw1[ps] = ((unsigned)(s & 511) << 23) | wq;
    }
}

// Pass D': per-src-bucket LDS reduction -> deg -> dinv.
__global__ __launch_bounds__(256) void passDp(const unsigned* __restrict__ sw1,
                                              const int* __restrict__ gbase,
                                              float* __restrict__ dinv) {
    __shared__ float acc[512];
    int k = blockIdx.x, t = threadIdx.x;
    acc[t] = 0.f;
    acc[t + 256] = 0.f;
    __syncthreads();
    int s0 = gbase[257 + k], s1 = gbase[257 + k + 1];
    for (int p = s0 + t; p < s1; p += 256) {
        unsigned v = sw1[p];
        atomicAdd(&acc[v >> 23], (float)(v & 8388607u) * (1.f / 8388608.f));
    }
    __syncthreads();
    for (int i = t; i < 512; i += 256) {
        float dg = acc[i];
        dinv[(k << 9) + i] = dg > 0.f ? rsqrtf(dg) : 0.f;
    }
}

// Pass D: local counting sort within each dst bucket -> cs2 + row_ptr.
__global__ __launch_bounds__(256) void passD(const int2* __restrict__ cs1,
                                             const int* __restrict__ gbase,
                                             unsigned* __restrict__ cs2,
                                             int* __restrict__ row_ptr) {
    __shared__ int hist[512], curs[512], tpre[256];
    int k = blockIdx.x, t = threadIdx.x;
    hist[t] = 0;
    hist[t + 256] = 0;
    __syncthreads();
    int s0 = gbase[k], s1 = gbase[k + 1];
    for (int p = s0 + t; p < s1; p += 256)
        atomicAdd(&hist[(unsigned)cs1[p].x >> 17], 1);
    __syncthreads();
    int v0 = hist[2 * t], v1 = hist[2 * t + 1];
    tpre[t] = v0 + v1;
    __syncthreads();
    for (int off = 1; off < 256; off <<= 1) {
        int v = (t >= off) ? tpre[t - off] : 0;
        __syncthreads();
        tpre[t] += v;
        __syncthreads();
    }
    int excl = tpre[t] - (v0 + v1);
    curs[2 * t] = excl;
    curs[2 * t + 1] = excl + v0;
    int nid = (k << 9) + 2 * t;
    row_ptr[nid] = s0 + excl;
    row_ptr[nid + 1] = s0 + excl + v0;
    if (k == K1 - 1 && t == 255) row_ptr[N_NODES] = N_EDGES;
    __syncthreads();
    for (int p = s0 + t; p < s1; p += 256) {
        int2 e = cs1[p];
        unsigned dl = (unsigned)e.x >> 17;
        int src = e.x & 0x1FFFF;
        float w = __int_as_float(e.y);
        unsigned wq = (unsigned)(w * 32768.f);
        if (wq > 32767u) wq = 32767u;
        int pos = s0 + atomicAdd(&curs[dl], 1);
        cs2[pos] = ((unsigned)src << 15) | wq;
    }
}

// ---------------------------------------------------------------------------
// x16 = f16(dinv .* x)
__global__ void xscale16(const float* __restrict__ x, const float* __restrict__ dinv,
                         __half* __restrict__ x16) {
    int i = blockIdx.x * 256 + threadIdx.x;
    x16[i] = __float2half(dinv[i >> 6] * x[i]);
}

// Pull SpMM with fp16 gathers (unchanged from round 12).
__global__ __launch_bounds__(256) void spmm_pull16(
    const int* __restrict__ row_ptr, const unsigned* __restrict__ cs,
    const __half* __restrict__ v16, const float* __restrict__ prev,
    const float* __restrict__ dinv, float* __restrict__ y32,
    __half* __restrict__ y16, float scale, float beta, int scaled16) {
    int lane = threadIdx.x & 63;
    int node = (blockIdx.x << 2) + (threadIdx.x >> 6);
    int s0 = row_ptr[node];
    int s1 = row_ptr[node + 1];
    float acc = 0.f;
    int p = s0;
    for (; p + 3 < s1; p += 4) {
        unsigned e0 = cs[p], e1 = cs[p + 1], e2 = cs[p + 2], e3 = cs[p + 3];
        float v0 = __half2float(v16[(size_t)(e0 >> 15) * FDIM + lane]);
        float v1 = __half2float(v16[(size_t)(e1 >> 15) * FDIM + lane]);
        float v2 = __half2float(v16[(size_t)(e2 >> 15) * FDIM + lane]);
        float v3 = __half2float(v16[(size_t)(e3 >> 15) * FDIM + lane]);
        acc = fmaf(((e0 & 32767u) + 0.5f) * (1.f / 32768.f), v0, acc);
        acc = fmaf(((e1 & 32767u) + 0.5f) * (1.f / 32768.f), v1, acc);
        acc = fmaf(((e2 & 32767u) + 0.5f) * (1.f / 32768.f), v2, acc);
        acc = fmaf(((e3 & 32767u) + 0.5f) * (1.f / 32768.f), v3, acc);
    }
    for (; p < s1; ++p) {
        unsigned e0 = cs[p];
        acc = fmaf(((e0 & 32767u) + 0.5f) * (1.f / 32768.f),
                   __half2float(v16[(size_t)(e0 >> 15) * FDIM + lane]), acc);
    }
    size_t o = (size_t)node * FDIM + lane;
    float di = dinv[node];
    float y = scale * (-di) * acc;
    if (beta != 0.f) y += beta * prev[o];
    if (y32) y32[o] = y;
    if (y16) y16[o] = __float2half(scaled16 ? di * y : y);
}

// ---------------------------------------------------------------------------
// Repack weights into MFMA B-fragment order (f16), one-time.
// Packed col pc: wave w = pc>>6 handles gate-cols [w*32, w*32+32);
//   i = pc&63: i<32 -> z (gate 0) col w*32+i ; i>=32 -> t (gate 2) col w*32+i-32.
// Fragment order: for k = kt*32 + g*8 + j (lane group g = lane>>4, reg j):
//   Wpack[((kt*256 + pc)*4 + g)*8 + j]
__global__ void repack_w(const float* __restrict__ Wx, __half* __restrict__ Wpack) {
    int k = blockIdx.x;    // 0..255 combined K
    int pc = threadIdx.x;  // 0..255 packed col
    int w = pc >> 6, i = pc & 63;
    int gate = (i < 32) ? 0 : 2;
    int c = w * 32 + (i & 31);
    float v = Wx[((size_t)gate * 256 + k) * 128 + c];
    int kt = k >> 5, g = (k >> 3) & 3, j = k & 7;
    Wpack[(((size_t)kt * 256 + pc) * 4 + g) * 8 + j] = __float2half(v);
}

// MFMA gate GEMM: block = 256 thr = 4 waves, 64 nodes. Wave w computes
// packed cols [w*64, w*64+64) = gate-cols [w*32,+32) for BOTH z and t ->
// activation is lane-local. A staged in LDS f16 [64][264] (528B pitch:
// bank start 4*((row+lg)&7)+16*(kt&1), 8 quads x 8 lanes = conflict-free
// b128). B-fragments loaded straight from L2-resident Wpack (16B/lane).
// C/D layout (m89): col=lane&15, row=(lane>>4)*4+reg.
__global__ __launch_bounds__(256) void gate_mfma(
    const float* __restrict__ x, const float* __restrict__ tx1,
    const float* __restrict__ tx2, const __half* __restrict__ tx3h,
    const __half* __restrict__ Wpack, const float* __restrict__ bx,
    const float* __restrict__ bh, const float* __restrict__ Wlin,
    const float* __restrict__ blin, float* __restrict__ outv,
    float* __restrict__ logits) {
    __shared__ __half Alds[64 * 264];  // row pitch 264 f16 = 528 B
    __shared__ float sums[64], sumw[64];
    int tid = threadIdx.x;
    long long nodeBase = (long long)blockIdx.x * 64;

    if (tid < 64) {
        sums[tid] = 0.f;
        sumw[tid] = 0.f;
    }
    // ---- stage A (f16): row = tid>>2, 16-feat quarter q = tid&3, 4 cheb blocks
    {
        int row = tid >> 2, q = tid & 3;
        long long node = nodeBase + row;
        const float* srcs[3] = {x, tx1, tx2};
#pragma unroll
        for (int c = 0; c < 3; ++c) {
            const float4* sp = (const float4*)(srcs[c] + (size_t)node * FDIM + q * 16);
            float4 v0 = sp[0], v1 = sp[1], v2 = sp[2], v3 = sp[3];
            f16x8 h0, h1;
            h0[0] = (_Float16)v0.x; h0[1] = (_Float16)v0.y;
            h0[2] = (_Float16)v0.z; h0[3] = (_Float16)v0.w;
            h0[4] = (_Float16)v1.x; h0[5] = (_Float16)v1.y;
            h0[6] = (_Float16)v1.z; h0[7] = (_Float16)v1.w;
            h1[0] = (_Float16)v2.x; h1[1] = (_Float16)v2.y;
            h1[2] = (_Float16)v2.z; h1[3] = (_Float16)v2.w;
            h1[4] = (_Float16)v3.x; h1[5] = (_Float16)v3.y;
            h1[6] = (_Float16)v3.z; h1[7] = (_Float16)v3.w;
            __half* dp = &Alds[row * 264 + c * 64 + q * 16];
            *(f16x8*)dp = h0;
            *(f16x8*)(dp + 8) = h1;
        }
        const f16x8* sp3 = (const f16x8*)(tx3h + (size_t)node * FDIM + q * 16);
        __half* dp3 = &Alds[row * 264 + 192 + q * 16];
        *(f16x8*)dp3 = sp3[0];
        *(f16x8*)(dp3 + 8) = sp3[1];
    }
    __syncthreads();

    int l = tid & 63, w = tid >> 6;
    int lg = l >> 4;  // 0..3 (k-group)
    int ln = l & 15;  // row (A) / col (B,C)

    f32x4 acc[4][4];
#pragma unroll
    for (int rt = 0; rt < 4; ++rt)
#pragma unroll
        for (int ct = 0; ct < 4; ++ct) acc[rt][ct] = (f32x4){0.f, 0.f, 0.f, 0.f};

    for (int kt = 0; kt < 8; ++kt) {
        f16x8 aF[4], bF[4];
#pragma unroll
        for (int rt = 0; rt < 4; ++rt)
            aF[rt] = *(const f16x8*)&Alds[(rt * 16 + ln) * 264 + kt * 32 + lg * 8];
#pragma unroll
        for (int ct = 0; ct < 4; ++ct)
            bF[ct] = *(const f16x8*)(Wpack +
                     (((size_t)(kt * 256 + w * 64 + ct * 16 + ln) * 4 + lg) << 3));
#pragma unroll
        for (int rt = 0; rt < 4; ++rt)
#pragma unroll
            for (int ct = 0; ct < 4; ++ct)
                acc[rt][ct] = __builtin_amdgcn_mfma_f32_16x16x32_f16(
                    aF[rt], bF[ct], acc[rt][ct], 0, 0, 0);
    }

    // ---- epilogue: z tile (ct2) pairs with t tile (ct2+2), same lane/reg.
    float bzv[2], btv[2], wlv[2];
#pragma unroll
    for (int ct2 = 0; ct2 < 2; ++ct2) {
        int c = w * 32 + ct2 * 16 + ln;  // gate col 0..127
        bzv[ct2] = bx[c] + bh[c];
        btv[ct2] = bx[256 + c] + bh[256 + c];
        wlv[ct2] = Wlin[c];
    }
#pragma unroll
    for (int rt = 0; rt < 4; ++rt) {
        float sh[4] = {0.f, 0.f, 0.f, 0.f};
        float sw_[4] = {0.f, 0.f, 0.f, 0.f};
#pragma unroll
        for (int ct2 = 0; ct2 < 2; ++ct2) {
            f32x4 zq = acc[rt][ct2];
            f32x4 tq = acc[rt][ct2 + 2];
#pragma unroll
            for (int r = 0; r < 4; ++r) {
                float pz = zq[r] + bzv[ct2];
                float pt = tq[r] + btv[ct2];
                float zg = 1.f / (1.f + __expf(-pz));
                float e2 = __expf(2.f * pt);
                float ht = 1.f - 2.f / (e2 + 1.f);
                float h = (1.f - zg) * ht;
                h = h > 0.f ? h : 0.f;
                sh[r] += h;
                sw_[r] += h * wlv[ct2];
            }
        }
#pragma unroll
        for (int off = 1; off < 16; off <<= 1) {
#pragma unroll
            for (int r = 0; r < 4; ++r) {
                sh[r] += __shfl_xor(sh[r], off, 64);
                sw_[r] += __shfl_xor(sw_[r], off, 64);
            }
        }
        if (ln == 0) {
#pragma unroll
            for (int r = 0; r < 4; ++r) {
                int row = rt * 16 + lg * 4 + r;
                atomicAdd(&sums[row], sh[r]);
                atomicAdd(&sumw[row], sw_[r]);
            }
        }
    }
    __syncthreads();
    if (tid < 64) {
        logits[nodeBase + tid] = sqrtf(sums[tid]);
        outv[nodeBase + tid] = sumw[tid] + blin[0];
    }
}

// ---------------------------------------------------------------------------
extern "C" void kernel_launch(void* const* d_in, const int* in_sizes, int n_in,
                              void* d_out, int out_size, void* d_ws, size_t ws_size,
                              hipStream_t stream) {
    const float* x = (const float*)d_in[0];
    const void* ei = d_in[1];
    const float* ew = (const float*)d_in[2];
    const float* Wx = (const float*)d_in[3];
    const float* bx = (const float*)d_in[5];
    const float* bh = (const float*)d_in[6];
    const float* Wlin = (const float*)d_in[7];
    const float* blin = (const float*)d_in[8];
    float* outv = (float*)d_out;
    float* logits = (float*)d_out + N_NODES;

    // workspace (words); every buffer fully written before read -> no memsets
    float* dinv = (float*)d_ws;                         // N
    int* flag = (int*)(dinv + N_NODES);                 // 64
    int* row_ptr = flag + 64;                           // N + 64
    int* hist_d = row_ptr + N_NODES + 64;               // 512*256
    int* hist_s = hist_d + BPASS * K1;                  // 512*256
    int* off2_d = hist_s + BPASS * K1;                  // 512*256
    int* off2_s = off2_d + BPASS * K1;                  // 512*256
    int* colsum = off2_s + BPASS * K1;                  // 512
    int* gbase = colsum + 512;                          // 514 (pad 576)
    int2* cs1 = (int2*)(gbase + 576);                   // E int2   (32 MiB)
    unsigned* sw1 = (unsigned*)(cs1 + N_EDGES);         // E words  (16 MiB)
    unsigned* cs2 = sw1;                                // alias: sw1 dead after passDp
    float* tx1 = (float*)cs1;                           // alias: cs1 dead after passD
    float* tx2 = (float*)(sw1 + N_EDGES);               // N*64 f32 (32 MiB)
    __half* tx3h = (__half*)(tx2 + (size_t)N_NODES * FDIM);   // N*64 f16
    __half* x16 = tx3h + (size_t)N_NODES * FDIM;        // N*64 f16
    __half* t116 = x16 + (size_t)N_NODES * FDIM;        // N*64 f16
    __half* t216 = x16;                                 // alias: x16 dead after spmm1
    __half* Wpack = t116 + (size_t)N_NODES * FDIM;      // 64K f16 (128 KiB)

    detect_i64<<<1, 256, 0, stream>>>((const int*)ei, flag);
    repack_w<<<256, 256, 0, stream>>>(Wx, Wpack);
    passA<<<BPASS, 256, 0, stream>>>(ei, flag, hist_d, hist_s);
    s1_colsum<<<512, 256, 0, stream>>>(hist_d, hist_s, colsum);
    s2_scan<<<1, 256, 0, stream>>>(colsum, gbase);
    s3_off2<<<512, 256, 0, stream>>>(hist_d, hist_s, gbase, off2_d, off2_s);
    passC<<<BPASS, 256, 0, stream>>>(ei, ew, flag, off2_d, off2_s, cs1, sw1);
    passDp<<<K1, 256, 0, stream>>>(sw1, gbase, dinv);
    passD<<<K1, 256, 0, stream>>>(cs1, gbase, cs2, row_ptr);
    xscale16<<<N_NODES * FDIM / 256, 256, 0, stream>>>(x, dinv, x16);

    // Tx1 = L x ; write f32 + scaled f16
    spmm_pull16<<<N_NODES / 4, 256, 0, stream>>>(row_ptr, cs2, x16, x, dinv,
                                                 tx1, t116, 1.f, 0.f, 1);
    // Tx2 = 2 L Tx1 - x
    spmm_pull16<<<N_NODES / 4, 256, 0, stream>>>(row_ptr, cs2, t116, x, dinv,
                                                 tx2, t216, 2.f, -1.f, 1);
    // Tx3 = 2 L Tx2 - Tx1 ; only f16 (unscaled) needed, for the gate GEMM
    spmm_pull16<<<N_NODES / 4, 256, 0, stream>>>(row_ptr, cs2, t216, tx1, dinv,
                                                 nullptr, tx3h, 2.f, -1.f, 0);

    gate_mfma<<<N_NODES / 64, 256, 0, stream>>>(x, tx1, tx2, tx3h, Wpack, bx, bh,
                                                Wlin, blin, outv, logits);
}

// Round 14
// 702.190 us; speedup vs baseline: 5.6911x; 1.1528x over previous
//
#include <hip/hip_runtime.h>
#include <hip/hip_fp16.h>

#define N_NODES 131072
#define N_EDGES 4194304
#define FDIM 64
#define HID 128
#define BPASS 512            // blocks in edge passes (A, C)
#define EPB (N_EDGES / BPASS)  // 8192 edges per block
#define K1 256               // coarse buckets (512 nodes each)

typedef _Float16 f16x8 __attribute__((ext_vector_type(8)));
typedef float f32x4 __attribute__((ext_vector_type(4)));

// ---------------------------------------------------------------------------
__global__ void detect_i64(const int* __restrict__ ei, int* __restrict__ flag) {
    __shared__ int s_nz;
    int t = threadIdx.x;
    if (t == 0) s_nz = 0;
    __syncthreads();
    if (ei[2 * t + 1] != 0) atomicAdd(&s_nz, 1);
    __syncthreads();
    if (t == 0) *flag = (s_nz == 0) ? 1 : 0;
}

__device__ __forceinline__ int load_idx(const void* ei, long long pos, int is64) {
    if (is64) return (int)((const long long*)ei)[pos];
    return ((const int*)ei)[pos];
}

// ---------------------------------------------------------------------------
// Pass A: per-block coarse histograms (dst>>9 and src>>9). No global atomics.
__global__ __launch_bounds__(256) void passA(const void* __restrict__ ei,
                                             const int* __restrict__ flag,
                                             int* __restrict__ hist_d,
                                             int* __restrict__ hist_s) {
    __shared__ int hd[K1], hs[K1];
    int t = threadIdx.x, b = blockIdx.x;
    hd[t] = 0;
    hs[t] = 0;
    __syncthreads();
    int is64 = *flag;
    long long base = (long long)b * EPB;
    for (int it = 0; it < EPB / 256; ++it) {
        long long e = base + it * 256 + t;
        int s = load_idx(ei, e, is64);
        int d = load_idx(ei, N_EDGES + e, is64);
        atomicAdd(&hd[d >> 9], 1);
        atomicAdd(&hs[s >> 9], 1);
    }
    __syncthreads();
    hist_d[b * K1 + t] = hd[t];
    hist_s[b * K1 + t] = hs[t];
}

// S1: column sums. Block j<256: dst column j; else src column j-256.
__global__ void s1_colsum(const int* __restrict__ hist_d, const int* __restrict__ hist_s,
                          int* __restrict__ colsum) {
    int j = blockIdx.x;
    const int* h = (j < K1) ? hist_d : hist_s;
    int col = j & (K1 - 1);
    __shared__ int red[256];
    int t = threadIdx.x;
    red[t] = h[t * K1 + col] + h[(t + 256) * K1 + col];
    __syncthreads();
    for (int off = 128; off > 0; off >>= 1) {
        if (t < off) red[t] += red[t + off];
        __syncthreads();
    }
    if (t == 0) colsum[j] = red[0];
}

// S2: exclusive scans of the two 256-entry colsum halves -> gbase (edge units).
__global__ void s2_scan(const int* __restrict__ colsum, int* __restrict__ gbase) {
    __shared__ int tmp[256];
    int t = threadIdx.x;
    tmp[t] = colsum[t];
    __syncthreads();
    for (int off = 1; off < 256; off <<= 1) {
        int v = (t >= off) ? tmp[t - off] : 0;
        __syncthreads();
        tmp[t] += v;
        __syncthreads();
    }
    gbase[t] = tmp[t] - colsum[t];
    if (t == 255) gbase[256] = tmp[255];
    __syncthreads();
    tmp[t] = colsum[256 + t];
    __syncthreads();
    for (int off = 1; off < 256; off <<= 1) {
        int v = (t >= off) ? tmp[t - off] : 0;
        __syncthreads();
        tmp[t] += v;
        __syncthreads();
    }
    gbase[257 + t] = tmp[t] - colsum[256 + t];
    if (t == 255) gbase[513] = tmp[255];
}

// S3: per-bucket column scan over blocks -> per-(block,bucket) reservations.
__global__ void s3_off2(const int* __restrict__ hist_d, const int* __restrict__ hist_s,
                        const int* __restrict__ gbase, int* __restrict__ off2_d,
                        int* __restrict__ off2_s) {
    int j = blockIdx.x;
    const int* h = (j < K1) ? hist_d : hist_s;
    int* off2 = (j < K1) ? off2_d : off2_s;
    int col = j & (K1 - 1);
    int base = (j < K1) ? gbase[col] : gbase[257 + col];
    __shared__ int tpre[256];
    int t = threadIdx.x;
    int v0 = h[(2 * t) * K1 + col];
    int v1 = h[(2 * t + 1) * K1 + col];
    tpre[t] = v0 + v1;
    __syncthreads();
    for (int off = 1; off < 256; off <<= 1) {
        int v = (t >= off) ? tpre[t - off] : 0;
        __syncthreads();
        tpre[t] += v;
        __syncthreads();
    }
    int excl = tpre[t] - (v0 + v1);
    off2[(2 * t) * K1 + col] = base + excl;
    off2[(2 * t + 1) * K1 + col] = base + excl + v0;
}

// Pass C: scatter edges into reserved coarse-bucket chunks.
__global__ __launch_bounds__(256) void passC(const void* __restrict__ ei,
                                             const float* __restrict__ ew,
                                             const int* __restrict__ flag,
                                             const int* __restrict__ off2_d,
                                             const int* __restrict__ off2_s,
                                             int2* __restrict__ cs1,
                                             unsigned* __restrict__ sw1) {
    __shared__ int curD[K1], curS[K1];
    int t = threadIdx.x, b = blockIdx.x;
    curD[t] = off2_d[b * K1 + t];
    curS[t] = off2_s[b * K1 + t];
    __syncthreads();
    int is64 = *flag;
    long long base = (long long)b * EPB;
    for (int it = 0; it < EPB / 256; ++it) {
        long long e = base + it * 256 + t;
        int s = load_idx(ei, e, is64);
        int d = load_idx(ei, N_EDGES + e, is64);
        float w = ew[e];
        int pd = atomicAdd(&curD[d >> 9], 1);
        cs1[pd] = make_int2(((d & 511) << 17) | s, __float_as_int(w));
        unsigned wq = (unsigned)(w * 8388608.f);
        if (wq > 8388607u) wq = 8388607u;
        int ps = atomicAdd(&curS[s >> 9], 1);
        sw1[ps] = ((unsigned)(s & 511) << 23) | wq;
    }
}

// Pass D': per-src-bucket LDS reduction -> deg -> dinv.
__global__ __launch_bounds__(256) void passDp(const unsigned* __restrict__ sw1,
                                              const int* __restrict__ gbase,
                                              float* __restrict__ dinv) {
    __shared__ float acc[512];
    int k = blockIdx.x, t = threadIdx.x;
    acc[t] = 0.f;
    acc[t + 256] = 0.f;
    __syncthreads();
    int s0 = gbase[257 + k], s1 = gbase[257 + k + 1];
    for (int p = s0 + t; p < s1; p += 256) {
        unsigned v = sw1[p];
        atomicAdd(&acc[v >> 23], (float)(v & 8388607u) * (1.f / 8388608.f));
    }
    __syncthreads();
    for (int i = t; i < 512; i += 256) {
        float dg = acc[i];
        dinv[(k << 9) + i] = dg > 0.f ? rsqrtf(dg) : 0.f;
    }
}

// Pass D: local counting sort within each dst bucket -> cs2 + row_ptr.
__global__ __launch_bounds__(256) void passD(const int2* __restrict__ cs1,
                                             const int* __restrict__ gbase,
                                             unsigned* __restrict__ cs2,
                                             int* __restrict__ row_ptr) {
    __shared__ int hist[512], curs[512], tpre[256];
    int k = blockIdx.x, t = threadIdx.x;
    hist[t] = 0;
    hist[t + 256] = 0;
    __syncthreads();
    int s0 = gbase[k], s1 = gbase[k + 1];
    for (int p = s0 + t; p < s1; p += 256)
        atomicAdd(&hist[(unsigned)cs1[p].x >> 17], 1);
    __syncthreads();
    int v0 = hist[2 * t], v1 = hist[2 * t + 1];
    tpre[t] = v0 + v1;
    __syncthreads();
    for (int off = 1; off < 256; off <<= 1) {
        int v = (t >= off) ? tpre[t - off] : 0;
        __syncthreads();
        tpre[t] += v;
        __syncthreads();
    }
    int excl = tpre[t] - (v0 + v1);
    curs[2 * t] = excl;
    curs[2 * t + 1] = excl + v0;
    int nid = (k << 9) + 2 * t;
    row_ptr[nid] = s0 + excl;
    row_ptr[nid + 1] = s0 + excl + v0;
    if (k == K1 - 1 && t == 255) row_ptr[N_NODES] = N_EDGES;
    __syncthreads();
    for (int p = s0 + t; p < s1; p += 256) {
        int2 e = cs1[p];
        unsigned dl = (unsigned)e.x >> 17;
        int src = e.x & 0x1FFFF;
        float w = __int_as_float(e.y);
        unsigned wq = (unsigned)(w * 32768.f);
        if (wq > 32767u) wq = 32767u;
        int pos = s0 + atomicAdd(&curs[dl], 1);
        cs2[pos] = ((unsigned)src << 15) | wq;
    }
}

// ---------------------------------------------------------------------------
// x16 = f16(dinv .* x)
__global__ void xscale16(const float* __restrict__ x, const float* __restrict__ dinv,
                         __half* __restrict__ x16) {
    int i = blockIdx.x * 256 + threadIdx.x;
    x16[i] = __float2half(dinv[i >> 6] * x[i]);
}

// Pull SpMM, half2 gathers: lane = (h = lane>>5: edge parity, fl = lane&31:
// feature pair 2fl,2fl+1). Half-wave h processes edge p+h; each lane loads
// __half2 (4 B; 32 lanes = one 128-B row). f32 accumulation; final fold is
// one shfl_xor(32). Halves per-edge VALU + wave-level load instrs vs r13.
__global__ __launch_bounds__(256) void spmm_pull16(
    const int* __restrict__ row_ptr, const unsigned* __restrict__ cs,
    const __half* __restrict__ v16, const float* __restrict__ prev,
    const float* __restrict__ dinv, float* __restrict__ y32,
    __half* __restrict__ y16, float scale, float beta, int scaled16) {
    int lane = threadIdx.x & 63;
    int h = lane >> 5;
    int fl = lane & 31;
    int node = (blockIdx.x << 2) + (threadIdx.x >> 6);
    int s0 = row_ptr[node];
    int s1 = row_ptr[node + 1];
    const char* vbase = (const char*)v16;
    float ax = 0.f, ay = 0.f;
    int p = s0;
    // 4 pairs = 8 edges per iteration; this half-wave handles p+2j+h.
    for (; p + 7 < s1; p += 8) {
        unsigned e0 = cs[p + 0 + h], e1 = cs[p + 2 + h];
        unsigned e2 = cs[p + 4 + h], e3 = cs[p + 6 + h];
        __half2 v0 = *(const __half2*)(vbase + (e0 >> 15) * 128u + fl * 4u);
        __half2 v1 = *(const __half2*)(vbase + (e1 >> 15) * 128u + fl * 4u);
        __half2 v2 = *(const __half2*)(vbase + (e2 >> 15) * 128u + fl * 4u);
        __half2 v3 = *(const __half2*)(vbase + (e3 >> 15) * 128u + fl * 4u);
        float w0 = ((e0 & 32767u) + 0.5f) * (1.f / 32768.f);
        float w1 = ((e1 & 32767u) + 0.5f) * (1.f / 32768.f);
        float w2 = ((e2 & 32767u) + 0.5f) * (1.f / 32768.f);
        float w3 = ((e3 & 32767u) + 0.5f) * (1.f / 32768.f);
        float2 f0 = __half22float2(v0), f1 = __half22float2(v1);
        float2 f2 = __half22float2(v2), f3 = __half22float2(v3);
        ax = fmaf(w0, f0.x, ax); ay = fmaf(w0, f0.y, ay);
        ax = fmaf(w1, f1.x, ax); ay = fmaf(w1, f1.y, ay);
        ax = fmaf(w2, f2.x, ax); ay = fmaf(w2, f2.y, ay);
        ax = fmaf(w3, f3.x, ax); ay = fmaf(w3, f3.y, ay);
    }
    for (; p < s1; p += 2) {
        int idx = p + h;
        if (idx < s1) {
            unsigned e0 = cs[idx];
            __half2 v0 = *(const __half2*)(vbase + (e0 >> 15) * 128u + fl * 4u);
            float w0 = ((e0 & 32767u) + 0.5f) * (1.f / 32768.f);
            float2 f0 = __half22float2(v0);
            ax = fmaf(w0, f0.x, ax);
            ay = fmaf(w0, f0.y, ay);
        }
    }
    ax += __shfl_xor(ax, 32, 64);
    ay += __shfl_xor(ay, 32, 64);
    float di = dinv[node];
    float yx = scale * (-di) * ax;
    float yy = scale * (-di) * ay;
    if (beta != 0.f) {
        float2 pv = ((const float2*)(prev + (size_t)node * FDIM))[fl];
        yx += beta * pv.x;
        yy += beta * pv.y;
    }
    if (h == 0) {
        if (y32) {
            float2 o;
            o.x = yx;
            o.y = yy;
            ((float2*)(y32 + (size_t)node * FDIM))[fl] = o;
        } else if (y16) {
            float sc = scaled16 ? di : 1.f;
            ((__half2*)(y16 + (size_t)node * FDIM))[fl] =
                __floats2half2_rn(sc * yx, sc * yy);
        }
    } else if (y32 && y16) {
        float sc = scaled16 ? di : 1.f;
        ((__half2*)(y16 + (size_t)node * FDIM))[fl] =
            __floats2half2_rn(sc * yx, sc * yy);
    }
}

// ---------------------------------------------------------------------------
// Repack weights into MFMA B-fragment order (f16), one-time.
__global__ void repack_w(const float* __restrict__ Wx, __half* __restrict__ Wpack) {
    int k = blockIdx.x;    // 0..255 combined K
    int pc = threadIdx.x;  // 0..255 packed col
    int w = pc >> 6, i = pc & 63;
    int gate = (i < 32) ? 0 : 2;
    int c = w * 32 + (i & 31);
    float v = Wx[((size_t)gate * 256 + k) * 128 + c];
    int kt = k >> 5, g = (k >> 3) & 3, j = k & 7;
    Wpack[(((size_t)kt * 256 + pc) * 4 + g) * 8 + j] = __float2half(v);
}

// MFMA gate GEMM (unchanged from round 13).
__global__ __launch_bounds__(256) void gate_mfma(
    const float* __restrict__ x, const float* __restrict__ tx1,
    const float* __restrict__ tx2, const __half* __restrict__ tx3h,
    const __half* __restrict__ Wpack, const float* __restrict__ bx,
    const float* __restrict__ bh, const float* __restrict__ Wlin,
    const float* __restrict__ blin, float* __restrict__ outv,
    float* __restrict__ logits) {
    __shared__ __half Alds[64 * 264];  // row pitch 264 f16 = 528 B
    __shared__ float sums[64], sumw[64];
    int tid = threadIdx.x;
    long long nodeBase = (long long)blockIdx.x * 64;

    if (tid < 64) {
        sums[tid] = 0.f;
        sumw[tid] = 0.f;
    }
    {
        int row = tid >> 2, q = tid & 3;
        long long node = nodeBase + row;
        const float* srcs[3] = {x, tx1, tx2};
#pragma unroll
        for (int c = 0; c < 3; ++c) {
            const float4* sp = (const float4*)(srcs[c] + (size_t)node * FDIM + q * 16);
            float4 v0 = sp[0], v1 = sp[1], v2 = sp[2], v3 = sp[3];
            f16x8 h0, h1;
            h0[0] = (_Float16)v0.x; h0[1] = (_Float16)v0.y;
            h0[2] = (_Float16)v0.z; h0[3] = (_Float16)v0.w;
            h0[4] = (_Float16)v1.x; h0[5] = (_Float16)v1.y;
            h0[6] = (_Float16)v1.z; h0[7] = (_Float16)v1.w;
            h1[0] = (_Float16)v2.x; h1[1] = (_Float16)v2.y;
            h1[2] = (_Float16)v2.z; h1[3] = (_Float16)v2.w;
            h1[4] = (_Float16)v3.x; h1[5] = (_Float16)v3.y;
            h1[6] = (_Float16)v3.z; h1[7] = (_Float16)v3.w;
            __half* dp = &Alds[row * 264 + c * 64 + q * 16];
            *(f16x8*)dp = h0;
            *(f16x8*)(dp + 8) = h1;
        }
        const f16x8* sp3 = (const f16x8*)(tx3h + (size_t)node * FDIM + q * 16);
        __half* dp3 = &Alds[row * 264 + 192 + q * 16];
        *(f16x8*)dp3 = sp3[0];
        *(f16x8*)(dp3 + 8) = sp3[1];
    }
    __syncthreads();

    int l = tid & 63, w = tid >> 6;
    int lg = l >> 4;
    int ln = l & 15;

    f32x4 acc[4][4];
#pragma unroll
    for (int rt = 0; rt < 4; ++rt)
#pragma unroll
        for (int ct = 0; ct < 4; ++ct) acc[rt][ct] = (f32x4){0.f, 0.f, 0.f, 0.f};

    for (int kt = 0; kt < 8; ++kt) {
        f16x8 aF[4], bF[4];
#pragma unroll
        for (int rt = 0; rt < 4; ++rt)
            aF[rt] = *(const f16x8*)&Alds[(rt * 16 + ln) * 264 + kt * 32 + lg * 8];
#pragma unroll
        for (int ct = 0; ct < 4; ++ct)
            bF[ct] = *(const f16x8*)(Wpack +
                     (((size_t)(kt * 256 + w * 64 + ct * 16 + ln) * 4 + lg) << 3));
#pragma unroll
        for (int rt = 0; rt < 4; ++rt)
#pragma unroll
            for (int ct = 0; ct < 4; ++ct)
                acc[rt][ct] = __builtin_amdgcn_mfma_f32_16x16x32_f16(
                    aF[rt], bF[ct], acc[rt][ct], 0, 0, 0);
    }

    float bzv[2], btv[2], wlv[2];
#pragma unroll
    for (int ct2 = 0; ct2 < 2; ++ct2) {
        int c = w * 32 + ct2 * 16 + ln;
        bzv[ct2] = bx[c] + bh[c];
        btv[ct2] = bx[256 + c] + bh[256 + c];
        wlv[ct2] = Wlin[c];
    }
#pragma unroll
    for (int rt = 0; rt < 4; ++rt) {
        float sh[4] = {0.f, 0.f, 0.f, 0.f};
        float sw_[4] = {0.f, 0.f, 0.f, 0.f};
#pragma unroll
        for (int ct2 = 0; ct2 < 2; ++ct2) {
            f32x4 zq = acc[rt][ct2];
            f32x4 tq = acc[rt][ct2 + 2];
#pragma unroll
            for (int r = 0; r < 4; ++r) {
                float pz = zq[r] + bzv[ct2];
                float pt = tq[r] + btv[ct2];
                float zg = 1.f / (1.f + __expf(-pz));
                float e2 = __expf(2.f * pt);
                float ht = 1.f - 2.f / (e2 + 1.f);
                float h = (1.f - zg) * ht;
                h = h > 0.f ? h : 0.f;
                sh[r] += h;
                sw_[r] += h * wlv[ct2];
            }
        }
#pragma unroll
        for (int off = 1; off < 16; off <<= 1) {
#pragma unroll
            for (int r = 0; r < 4; ++r) {
                sh[r] += __shfl_xor(sh[r], off, 64);
                sw_[r] += __shfl_xor(sw_[r], off, 64);
            }
        }
        if (ln == 0) {
#pragma unroll
            for (int r = 0; r < 4; ++r) {
                int row = rt * 16 + lg * 4 + r;
                atomicAdd(&sums[row], sh[r]);
                atomicAdd(&sumw[row], sw_[r]);
            }
        }
    }
    __syncthreads();
    if (tid < 64) {
        logits[nodeBase + tid] = sqrtf(sums[tid]);
        outv[nodeBase + tid] = sumw[tid] + blin[0];
    }
}

// ---------------------------------------------------------------------------
extern "C" void kernel_launch(void* const* d_in, const int* in_sizes, int n_in,
                              void* d_out, int out_size, void* d_ws, size_t ws_size,
                              hipStream_t stream) {
    const float* x = (const float*)d_in[0];
    const void* ei = d_in[1];
    const float* ew = (const float*)d_in[2];
    const float* Wx = (const float*)d_in[3];
    const float* bx = (const float*)d_in[5];
    const float* bh = (const float*)d_in[6];
    const float* Wlin = (const float*)d_in[7];
    const float* blin = (const float*)d_in[8];
    float* outv = (float*)d_out;
    float* logits = (float*)d_out + N_NODES;

    // workspace (words); every buffer fully written before read -> no memsets
    float* dinv = (float*)d_ws;                         // N
    int* flag = (int*)(dinv + N_NODES);                 // 64
    int* row_ptr = flag + 64;                           // N + 64
    int* hist_d = row_ptr + N_NODES + 64;               // 512*256
    int* hist_s = hist_d + BPASS * K1;                  // 512*256
    int* off2_d = hist_s + BPASS * K1;                  // 512*256
    int* off2_s = off2_d + BPASS * K1;                  // 512*256
    int* colsum = off2_s + BPASS * K1;                  // 512
    int* gbase = colsum + 512;                          // 514 (pad 576)
    int2* cs1 = (int2*)(gbase + 576);                   // E int2   (32 MiB)
    unsigned* sw1 = (unsigned*)(cs1 + N_EDGES);         // E words  (16 MiB)
    unsigned* cs2 = sw1;                                // alias: sw1 dead after passDp
    float* tx1 = (float*)cs1;                           // alias: cs1 dead after passD
    float* tx2 = (float*)(sw1 + N_EDGES);               // N*64 f32 (32 MiB)
    __half* tx3h = (__half*)(tx2 + (size_t)N_NODES * FDIM);   // N*64 f16
    __half* x16 = tx3h + (size_t)N_NODES * FDIM;        // N*64 f16
    __half* t116 = x16 + (size_t)N_NODES * FDIM;        // N*64 f16
    __half* t216 = x16;                                 // alias: x16 dead after spmm1
    __half* Wpack = t116 + (size_t)N_NODES * FDIM;      // 64K f16 (128 KiB)

    detect_i64<<<1, 256, 0, stream>>>((const int*)ei, flag);
    repack_w<<<256, 256, 0, stream>>>(Wx, Wpack);
    passA<<<BPASS, 256, 0, stream>>>(ei, flag, hist_d, hist_s);
    s1_colsum<<<512, 256, 0, stream>>>(hist_d, hist_s, colsum);
    s2_scan<<<1, 256, 0, stream>>>(colsum, gbase);
    s3_off2<<<512, 256, 0, stream>>>(hist_d, hist_s, gbase, off2_d, off2_s);
    passC<<<BPASS, 256, 0, stream>>>(ei, ew, flag, off2_d, off2_s, cs1, sw1);
    passDp<<<K1, 256, 0, stream>>>(sw1, gbase, dinv);
    passD<<<K1, 256, 0, stream>>>(cs1, gbase, cs2, row_ptr);
    xscale16<<<N_NODES * FDIM / 256, 256, 0, stream>>>(x, dinv, x16);

    // Tx1 = L x ; write f32 + scaled f16
    spmm_pull16<<<N_NODES / 4, 256, 0, stream>>>(row_ptr, cs2, x16, x, dinv,
                                                 tx1, t116, 1.f, 0.f, 1);
    // Tx2 = 2 L Tx1 - x
    spmm_pull16<<<N_NODES / 4, 256, 0, stream>>>(row_ptr, cs2, t116, x, dinv,
                                                 tx2, t216, 2.f, -1.f, 1);
    // Tx3 = 2 L Tx2 - Tx1 ; only f16 (unscaled) needed, for the gate GEMM
    spmm_pull16<<<N_NODES / 4, 256, 0, stream>>>(row_ptr, cs2, t216, tx1, dinv,
                                                 nullptr, tx3h, 2.f, -1.f, 0);

    gate_mfma<<<N_NODES / 64, 256, 0, stream>>>(x, tx1, tx2, tx3h, Wpack, bx, bh,
                                                Wlin, blin, outv, logits);
}